// Round 3
// baseline (1966.539 us; speedup 1.0000x reference)
//
#include <hip/hip_runtime.h>

typedef float f32x4 __attribute__((ext_vector_type(4)));

#define HD 128
#define TM 64

__device__ __forceinline__ float prelu_f(float x, float a) {
  return x > 0.f ? x : a * x;
}

// out = concat(node_scalar, node_vector)
__global__ __launch_bounds__(256) void init_out_kernel(
    const f32x4* __restrict__ ns, const f32x4* __restrict__ nv,
    f32x4* __restrict__ out, int n_ns4, int n_nv4)
{
  int total = n_ns4 + n_nv4;
  for (int i = blockIdx.x * 256 + threadIdx.x; i < total; i += gridDim.x * 256)
    out[i] = (i < n_ns4) ? ns[i] : nv[i - n_ns4];
}

// scalar-branch MLP: out[M,384] = prelu(prelu(A@w1+b1)@w2+b2)
__global__ __launch_bounds__(256) void node_mlp_kernel(
    const float* __restrict__ A,
    const float* __restrict__ w1, const float* __restrict__ b1, const float* __restrict__ a1p,
    const float* __restrict__ w2, const float* __restrict__ b2, const float* __restrict__ a2p,
    float* __restrict__ out, int M)
{
  __shared__ float A_lds[TM][HD];
  __shared__ float h_lds[TM][HD];
  const int t = threadIdx.x;
  const int tx = t & 31, ty = t >> 5;
  const int c4 = tx * 4;
  const int m0 = blockIdx.x * TM;
  const float a1 = a1p[0], a2 = a2p[0];

  for (int idx = t; idx < TM * HD / 4; idx += 256) {
    int r = idx >> 5;
    int cc = (idx & 31) * 4;
    f32x4 v = {0.f, 0.f, 0.f, 0.f};
    if (m0 + r < M) v = *(const f32x4*)&A[(size_t)(m0 + r) * HD + cc];
    *(f32x4*)&A_lds[r][cc] = v;
  }
  __syncthreads();

  float acc[8][4];
  {
    f32x4 bv = *(const f32x4*)&b1[c4];
    #pragma unroll
    for (int rr = 0; rr < 8; rr++)
      #pragma unroll
      for (int cc = 0; cc < 4; cc++) acc[rr][cc] = bv[cc];

    for (int kg = 0; kg < HD / 4; kg++) {
      const int k = kg * 4;
      f32x4 wv[4];
      #pragma unroll
      for (int kk = 0; kk < 4; kk++) wv[kk] = *(const f32x4*)&w1[(size_t)(k + kk) * HD + c4];
      #pragma unroll
      for (int rr = 0; rr < 8; rr++) {
        f32x4 av = *(const f32x4*)&A_lds[ty * 8 + rr][k];
        #pragma unroll
        for (int cc = 0; cc < 4; cc++)
          #pragma unroll
          for (int kk = 0; kk < 4; kk++)
            acc[rr][cc] += av[kk] * wv[kk][cc];
      }
    }
    #pragma unroll
    for (int rr = 0; rr < 8; rr++) {
      f32x4 hv;
      #pragma unroll
      for (int cc = 0; cc < 4; cc++) hv[cc] = prelu_f(acc[rr][cc], a1);
      *(f32x4*)&h_lds[ty * 8 + rr][c4] = hv;
    }
  }
  __syncthreads();

  for (int m = 0; m < 3; m++) {
    f32x4 bv = *(const f32x4*)&b2[m * HD + c4];
    #pragma unroll
    for (int rr = 0; rr < 8; rr++)
      #pragma unroll
      for (int cc = 0; cc < 4; cc++) acc[rr][cc] = bv[cc];

    for (int kg = 0; kg < HD / 4; kg++) {
      const int k = kg * 4;
      f32x4 wv[4];
      #pragma unroll
      for (int kk = 0; kk < 4; kk++)
        wv[kk] = *(const f32x4*)&w2[(size_t)(k + kk) * 384 + m * HD + c4];
      #pragma unroll
      for (int rr = 0; rr < 8; rr++) {
        f32x4 av = *(const f32x4*)&h_lds[ty * 8 + rr][k];
        #pragma unroll
        for (int cc = 0; cc < 4; cc++)
          #pragma unroll
          for (int kk = 0; kk < 4; kk++)
            acc[rr][cc] += av[kk] * wv[kk][cc];
      }
    }
    #pragma unroll
    for (int rr = 0; rr < 8; rr++) {
      int r = ty * 8 + rr;
      if (m0 + r < M) {
        f32x4 ov;
        #pragma unroll
        for (int cc = 0; cc < 4; cc++) ov[cc] = prelu_f(acc[rr][cc], a2);
        *(f32x4*)&out[(size_t)(m0 + r) * 384 + m * HD + c4] = ov;
      }
    }
  }
}

// ---------------- CSR build ----------------
__global__ __launch_bounds__(256) void zero_int_kernel(int* __restrict__ p, int n) {
  int i = blockIdx.x * 256 + threadIdx.x;
  if (i < n) p[i] = 0;
}

__global__ __launch_bounds__(256) void hist_kernel(const int* __restrict__ edge, int* __restrict__ counts, int E) {
  int e = blockIdx.x * 256 + threadIdx.x;
  if (e < E) atomicAdd(&counts[edge[(size_t)e * 2]], 1);
}

__global__ __launch_bounds__(1024) void scan_kernel(
    const int* __restrict__ counts, int* __restrict__ cursor, int n)
{
  __shared__ int sums[1024];
  const int t = threadIdx.x;
  const int per = (n + 1023) / 1024;
  const int lo = t * per, hi = min(lo + per, n);
  int s = 0;
  for (int i = lo; i < hi; i++) s += counts[i];
  sums[t] = s;
  __syncthreads();
  for (int off = 1; off < 1024; off <<= 1) {
    int v = sums[t];
    int u = (t >= off) ? sums[t - off] : 0;
    __syncthreads();
    sums[t] = v + u;
    __syncthreads();
  }
  int run = (t == 0) ? 0 : sums[t - 1];
  for (int i = lo; i < hi; i++) {
    cursor[i] = run;
    run += counts[i];
  }
}

__global__ __launch_bounds__(256) void scatter_ids_kernel(
    const int* __restrict__ edge, int* __restrict__ cursor, int* __restrict__ edge_list, int E)
{
  int e = blockIdx.x * 256 + threadIdx.x;
  if (e < E) {
    int d = edge[(size_t)e * 2];
    int p = atomicAdd(&cursor[d], 1);
    edge_list[p] = e;
  }
}

// ---------------- fused edge kernel: filter MLP + gather + gate +
// run-accumulated coalesced atomic scatter (dst-sorted order) ----------------
__global__ __launch_bounds__(256) void edge_scatter_kernel(
    const float* __restrict__ so,      // [N,384]
    const float* __restrict__ nv,      // [N,3,128]
    const int*   __restrict__ edge,    // [E,2] (dst, src)
    const float* __restrict__ diff,    // [E,3]
    const float* __restrict__ dist,    // [E]
    const float* __restrict__ rbf,     // [E,20]
    const int*   __restrict__ edge_list, // [E] edge ids sorted by dst
    const float* __restrict__ w1, const float* __restrict__ b1, const float* __restrict__ a1p,
    const float* __restrict__ w2, const float* __restrict__ b2, const float* __restrict__ a2p,
    float* __restrict__ out_s,         // [N,128]
    float* __restrict__ out_v,         // [N,3,128]
    int E)
{
  __shared__ float R_lds[TM][20];
  __shared__ float h_lds[TM][HD];
  __shared__ int   src_l[TM], dst_l[TM], eid_l[TM];
  __shared__ float unit_l[TM][3];

  const int t = threadIdx.x;
  const int tx = t & 31, ty = t >> 5;
  const int c4 = tx * 4;
  const int pblk = blockIdx.x * TM;
  const float a1 = a1p[0], a2 = a2p[0];

  if (t < TM) {
    int p = pblk + t;
    int e = (p < E) ? edge_list[p] : -1;
    eid_l[t] = e;
    if (e >= 0) {
      src_l[t] = edge[(size_t)e * 2 + 1];
      dst_l[t] = edge[(size_t)e * 2 + 0];
      float inv = 1.f / dist[e];
      unit_l[t][0] = diff[(size_t)e * 3 + 0] * inv;
      unit_l[t][1] = diff[(size_t)e * 3 + 1] * inv;
      unit_l[t][2] = diff[(size_t)e * 3 + 2] * inv;
    } else {
      src_l[t] = 0; dst_l[t] = -1;
    }
  }
  __syncthreads();

  for (int idx = t; idx < TM * 20; idx += 256) {
    int r = idx / 20, k = idx - r * 20;
    int e = eid_l[r];
    R_lds[r][k] = (e >= 0) ? rbf[(size_t)e * 20 + k] : 0.f;
  }
  __syncthreads();

  // ---- layer 1 (K=20) ----
  {
    float acc[8][4];
    f32x4 bv = *(const f32x4*)&b1[c4];
    #pragma unroll
    for (int rr = 0; rr < 8; rr++)
      #pragma unroll
      for (int cc = 0; cc < 4; cc++) acc[rr][cc] = bv[cc];

    for (int k = 0; k < 20; k++) {
      f32x4 wv = *(const f32x4*)&w1[(size_t)k * HD + c4];
      #pragma unroll
      for (int rr = 0; rr < 8; rr++) {
        float av = R_lds[ty * 8 + rr][k];
        #pragma unroll
        for (int cc = 0; cc < 4; cc++) acc[rr][cc] += av * wv[cc];
      }
    }
    #pragma unroll
    for (int rr = 0; rr < 8; rr++) {
      f32x4 hv;
      #pragma unroll
      for (int cc = 0; cc < 4; cc++) hv[cc] = prelu_f(acc[rr][cc], a1);
      *(f32x4*)&h_lds[ty * 8 + rr][c4] = hv;
    }
  }
  __syncthreads();

  // ---- layer 2: 3 gate planes, rows ty*8+rr (contiguous sorted positions) ----
  float acc2[3][8][4];
  #pragma unroll
  for (int m = 0; m < 3; m++) {
    f32x4 bv = *(const f32x4*)&b2[m * HD + c4];
    #pragma unroll
    for (int rr = 0; rr < 8; rr++)
      #pragma unroll
      for (int cc = 0; cc < 4; cc++) acc2[m][rr][cc] = bv[cc];
  }
  for (int kg = 0; kg < HD / 4; kg++) {
    const int k = kg * 4;
    f32x4 av[8];
    #pragma unroll
    for (int rr = 0; rr < 8; rr++) av[rr] = *(const f32x4*)&h_lds[ty * 8 + rr][k];
    #pragma unroll
    for (int m = 0; m < 3; m++) {
      f32x4 wv[4];
      #pragma unroll
      for (int kk = 0; kk < 4; kk++)
        wv[kk] = *(const f32x4*)&w2[(size_t)(k + kk) * 384 + m * HD + c4];
      #pragma unroll
      for (int rr = 0; rr < 8; rr++)
        #pragma unroll
        for (int cc = 0; cc < 4; cc++)
          #pragma unroll
          for (int kk = 0; kk < 4; kk++)
            acc2[m][rr][cc] += av[rr][kk] * wv[kk][cc];
    }
  }

  // ---- epilogue: gather + gate; run-accumulate over equal dst; atomic flush ----
  int cur_dst = -1;
  f32x4 as = {0.f, 0.f, 0.f, 0.f};
  f32x4 av0 = as, av1 = as, av2 = as;

  #pragma unroll
  for (int rr = 0; rr < 8; rr++) {
    const int r = ty * 8 + rr;
    const int dst = dst_l[r];
    if (dst >= 0) {
      if (dst != cur_dst) {
        if (cur_dst >= 0) {
          float* osp = &out_s[(size_t)cur_dst * HD + c4];
          #pragma unroll
          for (int cc = 0; cc < 4; cc++) atomicAdd(osp + cc, as[cc]);
          float* ovp = &out_v[(size_t)cur_dst * 3 * HD + c4];
          #pragma unroll
          for (int cc = 0; cc < 4; cc++) atomicAdd(ovp + cc, av0[cc]);
          #pragma unroll
          for (int cc = 0; cc < 4; cc++) atomicAdd(ovp + HD + cc, av1[cc]);
          #pragma unroll
          for (int cc = 0; cc < 4; cc++) atomicAdd(ovp + 2 * HD + cc, av2[cc]);
        }
        cur_dst = dst;
        #pragma unroll
        for (int cc = 0; cc < 4; cc++) { as[cc] = 0.f; av0[cc] = 0.f; av1[cc] = 0.f; av2[cc] = 0.f; }
      }
      const int src = src_l[r];
      const float u0 = unit_l[r][0], u1 = unit_l[r][1], u2 = unit_l[r][2];
      const size_t sb = (size_t)src * 384;
      f32x4 s0 = *(const f32x4*)&so[sb + c4];
      f32x4 s1 = *(const f32x4*)&so[sb + HD + c4];
      f32x4 s2 = *(const f32x4*)&so[sb + 2 * HD + c4];
      f32x4 gv, ms, ge;
      #pragma unroll
      for (int cc = 0; cc < 4; cc++) {
        gv[cc] = prelu_f(acc2[0][rr][cc], a2) * s0[cc];
        ms[cc] = prelu_f(acc2[1][rr][cc], a2) * s1[cc];
        ge[cc] = prelu_f(acc2[2][rr][cc], a2) * s2[cc];
      }
      const size_t nb = (size_t)src * 3 * HD;
      f32x4 nv0 = *(const f32x4*)&nv[nb + c4];
      f32x4 nv1 = *(const f32x4*)&nv[nb + HD + c4];
      f32x4 nv2 = *(const f32x4*)&nv[nb + 2 * HD + c4];
      #pragma unroll
      for (int cc = 0; cc < 4; cc++) {
        as[cc]  += ms[cc];
        av0[cc] += nv0[cc] * gv[cc] + u0 * ge[cc];
        av1[cc] += nv1[cc] * gv[cc] + u1 * ge[cc];
        av2[cc] += nv2[cc] * gv[cc] + u2 * ge[cc];
      }
    }
  }
  if (cur_dst >= 0) {
    float* osp = &out_s[(size_t)cur_dst * HD + c4];
    #pragma unroll
    for (int cc = 0; cc < 4; cc++) atomicAdd(osp + cc, as[cc]);
    float* ovp = &out_v[(size_t)cur_dst * 3 * HD + c4];
    #pragma unroll
    for (int cc = 0; cc < 4; cc++) atomicAdd(ovp + cc, av0[cc]);
    #pragma unroll
    for (int cc = 0; cc < 4; cc++) atomicAdd(ovp + HD + cc, av1[cc]);
    #pragma unroll
    for (int cc = 0; cc < 4; cc++) atomicAdd(ovp + 2 * HD + cc, av2[cc]);
  }
}

extern "C" void kernel_launch(void* const* d_in, const int* in_sizes, int n_in,
                              void* d_out, int out_size, void* d_ws, size_t ws_size,
                              hipStream_t stream)
{
  const float* node_scalar = (const float*)d_in[0];
  const float* node_vector = (const float*)d_in[1];
  const int*   che_edge = (const int*)d_in[2];
  const float* che_diff = (const float*)d_in[3];
  const float* che_dist = (const float*)d_in[4];
  const float* che_rbf  = (const float*)d_in[5];
  const int*   vdw_edge = (const int*)d_in[6];
  const float* vdw_diff = (const float*)d_in[7];
  const float* vdw_dist = (const float*)d_in[8];
  const float* vdw_rbf  = (const float*)d_in[9];
  const float* mlp_p[24];
  for (int i = 0; i < 24; i++) mlp_p[i] = (const float*)d_in[10 + i];
  // mlp_p layout: [che_s 0..5][che_f 6..11][vdw_s 12..17][vdw_f 18..23]

  const int N = in_sizes[0] / HD;
  const int E_che = in_sizes[4];
  const int E_vdw = in_sizes[8];
  const int E_max = E_che > E_vdw ? E_che : E_vdw;

  // workspace layout
  char* wp = (char*)d_ws;
  size_t off = 0;
  float* so = (float*)(wp + off);      off += (size_t)N * 384 * 4;
  int* counts    = (int*)(wp + off);   off += (size_t)N * 4;
  int* cursor    = (int*)(wp + off);   off += (size_t)N * 4;
  int* edge_list = (int*)(wp + off);   off += (size_t)E_max * 4;

  float* out_s = (float*)d_out;
  float* out_v = out_s + (size_t)N * HD;

  const int n_ns4 = N * HD / 4;
  const int n_nv4 = N * 3 * HD / 4;
  init_out_kernel<<<2048, 256, 0, stream>>>(
      (const f32x4*)node_scalar, (const f32x4*)node_vector, (f32x4*)d_out, n_ns4, n_nv4);

  for (int br = 0; br < 2; br++) {
    const int*   edge = br == 0 ? che_edge : vdw_edge;
    const float* diff = br == 0 ? che_diff : vdw_diff;
    const float* dist = br == 0 ? che_dist : vdw_dist;
    const float* rbf  = br == 0 ? che_rbf  : vdw_rbf;
    const int    E    = br == 0 ? E_che : E_vdw;
    const float* const* sp = &mlp_p[br == 0 ? 0 : 12];
    const float* const* fp = &mlp_p[br == 0 ? 6 : 18];

    node_mlp_kernel<<<(N + TM - 1) / TM, 256, 0, stream>>>(
        node_scalar, sp[0], sp[1], sp[2], sp[3], sp[4], sp[5], so, N);

    zero_int_kernel<<<(N + 255) / 256, 256, 0, stream>>>(counts, N);
    hist_kernel<<<(E + 255) / 256, 256, 0, stream>>>(edge, counts, E);
    scan_kernel<<<1, 1024, 0, stream>>>(counts, cursor, N);
    scatter_ids_kernel<<<(E + 255) / 256, 256, 0, stream>>>(edge, cursor, edge_list, E);

    edge_scatter_kernel<<<(E + TM - 1) / TM, 256, 0, stream>>>(
        so, node_vector, edge, diff, dist, rbf, edge_list,
        fp[0], fp[1], fp[2], fp[3], fp[4], fp[5], out_s, out_v, E);
  }
}

// Round 4
// 1853.226 us; speedup vs baseline: 1.0611x; 1.0611x over previous
//
#include <hip/hip_runtime.h>

typedef float f32x4 __attribute__((ext_vector_type(4)));
typedef short bf16x8 __attribute__((ext_vector_type(8)));

#define HD 128
#define TM 64
#define NB 16

__device__ __forceinline__ float prelu_f(float x, float a) {
  return x > 0.f ? x : a * x;
}

__device__ __forceinline__ unsigned short f2bf(float x) {
  union { float f; unsigned u; } a; a.f = x;
  unsigned r = a.u + 0x7fffu + ((a.u >> 16) & 1u);
  return (unsigned short)(r >> 16);
}
__device__ __forceinline__ float bf2f(unsigned short u) {
  union { unsigned u; float f; } a; a.u = ((unsigned)u) << 16;
  return a.f;
}
__device__ __forceinline__ f32x4 bf4_to_f32(ushort4 u) {
  f32x4 r; r[0] = bf2f(u.x); r[1] = bf2f(u.y); r[2] = bf2f(u.z); r[3] = bf2f(u.w);
  return r;
}

// ---------------- weight transpose+convert: w2[128][384] f32 -> w2t[384][128] bf16 ----------------
__global__ __launch_bounds__(256) void convert_w2_kernel(
    const float* __restrict__ w2a, unsigned short* __restrict__ w2ta,
    const float* __restrict__ w2b, unsigned short* __restrict__ w2tb)
{
  int idx = blockIdx.x * 256 + threadIdx.x;
  if (idx < 384 * 128) {
    int col = idx >> 7, k = idx & 127;
    w2ta[idx] = f2bf(w2a[(size_t)k * 384 + col]);
    w2tb[idx] = f2bf(w2b[(size_t)k * 384 + col]);
  }
}

// ---------------- node-scalar MLP (fp32 VALU): out[M,384] ----------------
__global__ __launch_bounds__(256) void node_mlp_kernel(
    const float* __restrict__ A,
    const float* __restrict__ w1, const float* __restrict__ b1, const float* __restrict__ a1p,
    const float* __restrict__ w2, const float* __restrict__ b2, const float* __restrict__ a2p,
    float* __restrict__ out, int M)
{
  __shared__ float A_lds[TM][HD];
  __shared__ float h_lds[TM][HD];
  const int t = threadIdx.x;
  const int tx = t & 31, ty = t >> 5;
  const int c4 = tx * 4;
  const int m0 = blockIdx.x * TM;
  const float a1 = a1p[0], a2 = a2p[0];

  for (int idx = t; idx < TM * HD / 4; idx += 256) {
    int r = idx >> 5;
    int cc = (idx & 31) * 4;
    f32x4 v = {0.f, 0.f, 0.f, 0.f};
    if (m0 + r < M) v = *(const f32x4*)&A[(size_t)(m0 + r) * HD + cc];
    *(f32x4*)&A_lds[r][cc] = v;
  }
  __syncthreads();

  float acc[8][4];
  {
    f32x4 bv = *(const f32x4*)&b1[c4];
    #pragma unroll
    for (int rr = 0; rr < 8; rr++)
      #pragma unroll
      for (int cc = 0; cc < 4; cc++) acc[rr][cc] = bv[cc];

    for (int kg = 0; kg < HD / 4; kg++) {
      const int k = kg * 4;
      f32x4 wv[4];
      #pragma unroll
      for (int kk = 0; kk < 4; kk++) wv[kk] = *(const f32x4*)&w1[(size_t)(k + kk) * HD + c4];
      #pragma unroll
      for (int rr = 0; rr < 8; rr++) {
        f32x4 av = *(const f32x4*)&A_lds[ty * 8 + rr][k];
        #pragma unroll
        for (int cc = 0; cc < 4; cc++)
          #pragma unroll
          for (int kk = 0; kk < 4; kk++)
            acc[rr][cc] += av[kk] * wv[kk][cc];
      }
    }
    #pragma unroll
    for (int rr = 0; rr < 8; rr++) {
      f32x4 hv;
      #pragma unroll
      for (int cc = 0; cc < 4; cc++) hv[cc] = prelu_f(acc[rr][cc], a1);
      *(f32x4*)&h_lds[ty * 8 + rr][c4] = hv;
    }
  }
  __syncthreads();

  for (int m = 0; m < 3; m++) {
    f32x4 bv = *(const f32x4*)&b2[m * HD + c4];
    #pragma unroll
    for (int rr = 0; rr < 8; rr++)
      #pragma unroll
      for (int cc = 0; cc < 4; cc++) acc[rr][cc] = bv[cc];

    for (int kg = 0; kg < HD / 4; kg++) {
      const int k = kg * 4;
      f32x4 wv[4];
      #pragma unroll
      for (int kk = 0; kk < 4; kk++)
        wv[kk] = *(const f32x4*)&w2[(size_t)(k + kk) * 384 + m * HD + c4];
      #pragma unroll
      for (int rr = 0; rr < 8; rr++) {
        f32x4 av = *(const f32x4*)&h_lds[ty * 8 + rr][k];
        #pragma unroll
        for (int cc = 0; cc < 4; cc++)
          #pragma unroll
          for (int kk = 0; kk < 4; kk++)
            acc[rr][cc] += av[kk] * wv[kk][cc];
      }
    }
    #pragma unroll
    for (int rr = 0; rr < 8; rr++) {
      int r = ty * 8 + rr;
      if (m0 + r < M) {
        f32x4 ov;
        #pragma unroll
        for (int cc = 0; cc < 4; cc++) ov[cc] = prelu_f(acc[rr][cc], a2);
        *(f32x4*)&out[(size_t)(m0 + r) * 384 + m * HD + c4] = ov;
      }
    }
  }
}

// ---------------- CSR build ----------------
__global__ __launch_bounds__(256) void zero_int_kernel(int* __restrict__ p, int n) {
  int i = blockIdx.x * 256 + threadIdx.x;
  if (i < n) p[i] = 0;
}

__global__ __launch_bounds__(256) void hist_kernel(const int* __restrict__ edge, int* __restrict__ counts, int E) {
  int e = blockIdx.x * 256 + threadIdx.x;
  if (e < E) atomicAdd(&counts[edge[(size_t)e * 2]], 1);
}

__global__ __launch_bounds__(1024) void scan_kernel(
    const int* __restrict__ counts, int* __restrict__ offsets, int* __restrict__ cursor, int n)
{
  __shared__ int sums[1024];
  const int t = threadIdx.x;
  const int per = (n + 1023) / 1024;
  const int lo = t * per, hi = min(lo + per, n);
  int s = 0;
  for (int i = lo; i < hi; i++) s += counts[i];
  sums[t] = s;
  __syncthreads();
  for (int off = 1; off < 1024; off <<= 1) {
    int v = sums[t];
    int u = (t >= off) ? sums[t - off] : 0;
    __syncthreads();
    sums[t] = v + u;
    __syncthreads();
  }
  int run = (t == 0) ? 0 : sums[t - 1];
  for (int i = lo; i < hi; i++) {
    offsets[i] = run;
    cursor[i] = run;
    run += counts[i];
  }
  if (t == 1023) offsets[n] = sums[1023];
}

__global__ __launch_bounds__(256) void scatter_ids_kernel(
    const int* __restrict__ edge, int* __restrict__ cursor, int* __restrict__ edge_list, int E)
{
  int e = blockIdx.x * 256 + threadIdx.x;
  if (e < E) {
    int d = edge[(size_t)e * 2];
    int p = atomicAdd(&cursor[d], 1);
    edge_list[p] = e;
  }
}

// ---------------- node-owned edge kernel: filter MLP (layer2 = bf16 MFMA),
// LDS plane staging, register accumulation, no global atomics ----------------
__global__ __launch_bounds__(256) void edge_mfma_kernel(
    const float* __restrict__ so,      // [N,384]
    const float* __restrict__ ns,      // [N,128] residual
    const float* __restrict__ nv,      // [N,3,128]
    const int*   __restrict__ edge,    // [E,2] (dst, src)
    const float* __restrict__ diff,    // [E,3]
    const float* __restrict__ dist,    // [E]
    const float* __restrict__ rbf,     // [E,20]
    const int*   __restrict__ edge_list,
    const int*   __restrict__ offsets, // [N+1]
    const float* __restrict__ w1, const float* __restrict__ b1, const float* __restrict__ a1p,
    const unsigned short* __restrict__ w2t, // [384][128] bf16
    const float* __restrict__ b2, const float* __restrict__ a2p,
    float* __restrict__ out_s,         // [N,128]
    float* __restrict__ out_v,         // [N,3,128]
    int N, int add_mode)
{
  __shared__ float R_lds[64][20];
  __shared__ __attribute__((aligned(16))) unsigned short h_lds[64 * 128];
  __shared__ __attribute__((aligned(16))) unsigned short P_lds[64 * 128];
  __shared__ int   eid_l[64], src_l[64];
  __shared__ float unit_l[64][3];
  __shared__ int   node_off[NB + 1];

  const int t = threadIdx.x;
  const int tx = t & 31, ty = t >> 5;
  const int c4 = tx * 4;
  const int wv = t >> 6;            // wave id 0..3
  const int lane = t & 63;
  const int l15 = lane & 15, l4 = lane >> 4;
  const int n0 = blockIdx.x * NB;
  const float a1 = a1p[0], a2 = a2p[0];

  if (t <= NB) node_off[t] = offsets[min(n0 + t, N)];
  const int w_start = offsets[min(n0, N)];
  const int w_end   = offsets[min(n0 + NB, N)];

  float accS[2][4];
  float accV[2][3][4];
  #pragma unroll
  for (int g = 0; g < 2; g++) {
    #pragma unroll
    for (int cc = 0; cc < 4; cc++) accS[g][cc] = 0.f;
    #pragma unroll
    for (int d = 0; d < 3; d++)
      #pragma unroll
      for (int cc = 0; cc < 4; cc++) accV[g][d][cc] = 0.f;
  }

  for (int base = w_start; base < w_end; base += 64) {
    const int nrows = min(64, w_end - base);
    __syncthreads();   // S0: prior tile's pass done before meta/R/h overwrite (also covers node_off on iter 0)

    if (t < 64) {
      int p = base + t;
      if (t < nrows) {
        int e = edge_list[p];
        eid_l[t] = e;
        src_l[t] = edge[(size_t)e * 2 + 1];
        float inv = 1.f / dist[e];
        unit_l[t][0] = diff[(size_t)e * 3 + 0] * inv;
        unit_l[t][1] = diff[(size_t)e * 3 + 1] * inv;
        unit_l[t][2] = diff[(size_t)e * 3 + 2] * inv;
      } else {
        eid_l[t] = -1; src_l[t] = 0;
        unit_l[t][0] = 0.f; unit_l[t][1] = 0.f; unit_l[t][2] = 0.f;
      }
    }
    __syncthreads();   // S1

    for (int idx = t; idx < 64 * 20; idx += 256) {
      int r = idx / 20, k = idx - r * 20;
      int e = eid_l[r];
      R_lds[r][k] = (e >= 0) ? rbf[(size_t)e * 20 + k] : 0.f;
    }
    __syncthreads();   // S2

    // ---- layer 1 (K=20, fp32 VALU) -> h_lds bf16 swizzled ----
    {
      float ha[8][4];
      f32x4 bv = *(const f32x4*)&b1[c4];
      #pragma unroll
      for (int rr = 0; rr < 8; rr++)
        #pragma unroll
        for (int cc = 0; cc < 4; cc++) ha[rr][cc] = bv[cc];
      for (int k = 0; k < 20; k++) {
        f32x4 wvv = *(const f32x4*)&w1[(size_t)k * HD + c4];
        #pragma unroll
        for (int rr = 0; rr < 8; rr++) {
          float av = R_lds[ty * 8 + rr][k];
          #pragma unroll
          for (int cc = 0; cc < 4; cc++) ha[rr][cc] += av * wvv[cc];
        }
      }
      #pragma unroll
      for (int rr = 0; rr < 8; rr++) {
        int row = ty * 8 + rr;
        ushort4 hp;
        hp.x = f2bf(prelu_f(ha[rr][0], a1));
        hp.y = f2bf(prelu_f(ha[rr][1], a1));
        hp.z = f2bf(prelu_f(ha[rr][2], a1));
        hp.w = f2bf(prelu_f(ha[rr][3], a1));
        *(ushort4*)&h_lds[row * 128 + (c4 ^ ((row & 7) << 3))] = hp;
      }
    }
    __syncthreads();   // S3

    // ---- layer 2: 3 planes (order: ms, gv, ge), MFMA + LDS stage + reg accumulate ----
    const int plane_order[3] = {1, 0, 2};
    #pragma unroll
    for (int pp = 0; pp < 3; pp++) {
      const int m = plane_order[pp];

      bf16x8 Bf[2][4];
      #pragma unroll
      for (int nf = 0; nf < 2; nf++)
        #pragma unroll
        for (int ks = 0; ks < 4; ks++) {
          int col = m * 128 + wv * 32 + nf * 16 + l15;
          Bf[nf][ks] = *(const bf16x8*)&w2t[(size_t)col * 128 + ks * 32 + l4 * 8];
        }

      f32x4 D[4][2];
      #pragma unroll
      for (int mi = 0; mi < 4; mi++)
        #pragma unroll
        for (int nf = 0; nf < 2; nf++)
          #pragma unroll
          for (int cc = 0; cc < 4; cc++) D[mi][nf][cc] = 0.f;

      #pragma unroll
      for (int mi = 0; mi < 4; mi++) {
        #pragma unroll
        for (int ks = 0; ks < 4; ks++) {
          int row = mi * 16 + l15;
          bf16x8 Af = *(const bf16x8*)&h_lds[row * 128 + ((ks * 32 + l4 * 8) ^ ((row & 7) << 3))];
          D[mi][0] = __builtin_amdgcn_mfma_f32_16x16x32_bf16(Af, Bf[0][ks], D[mi][0], 0, 0, 0);
          D[mi][1] = __builtin_amdgcn_mfma_f32_16x16x32_bf16(Af, Bf[1][ks], D[mi][1], 0, 0, 0);
        }
      }

      float b2v0 = b2[m * 128 + wv * 32 + l15];
      float b2v1 = b2[m * 128 + wv * 32 + 16 + l15];
      #pragma unroll
      for (int mi = 0; mi < 4; mi++)
        #pragma unroll
        for (int nf = 0; nf < 2; nf++)
          #pragma unroll
          for (int r4 = 0; r4 < 4; r4++) {
            int row = mi * 16 + l4 * 4 + r4;
            int col = wv * 32 + nf * 16 + l15;
            float v = prelu_f(D[mi][nf][r4] + (nf ? b2v1 : b2v0), a2);
            P_lds[row * 128 + (col ^ ((row & 7) << 3))] = f2bf(v);
          }
      __syncthreads();   // plane staged

      // accumulation pass over this block's node rows
      #pragma unroll
      for (int g = 0; g < 2; g++) {
        int nl = ty + 8 * g;
        int rs = node_off[nl] - base;     if (rs < 0) rs = 0;
        int re = node_off[nl + 1] - base; if (re > nrows) re = nrows;
        for (int r = rs; r < re; r++) {
          int src = src_l[r];
          ushort4 pu = *(const ushort4*)&P_lds[r * 128 + (c4 ^ ((r & 7) << 3))];
          f32x4 pv = bf4_to_f32(pu);
          if (m == 1) {
            f32x4 s1 = *(const f32x4*)&so[(size_t)src * 384 + 128 + c4];
            #pragma unroll
            for (int cc = 0; cc < 4; cc++) accS[g][cc] += pv[cc] * s1[cc];
          } else if (m == 0) {
            f32x4 s0 = *(const f32x4*)&so[(size_t)src * 384 + c4];
            f32x4 v0 = *(const f32x4*)&nv[(size_t)src * 384 + c4];
            f32x4 v1 = *(const f32x4*)&nv[(size_t)src * 384 + 128 + c4];
            f32x4 v2 = *(const f32x4*)&nv[(size_t)src * 384 + 256 + c4];
            #pragma unroll
            for (int cc = 0; cc < 4; cc++) {
              float gvv = pv[cc] * s0[cc];
              accV[g][0][cc] += v0[cc] * gvv;
              accV[g][1][cc] += v1[cc] * gvv;
              accV[g][2][cc] += v2[cc] * gvv;
            }
          } else {
            f32x4 s2 = *(const f32x4*)&so[(size_t)src * 384 + 256 + c4];
            float u0 = unit_l[r][0], u1 = unit_l[r][1], u2 = unit_l[r][2];
            #pragma unroll
            for (int cc = 0; cc < 4; cc++) {
              float gev = pv[cc] * s2[cc];
              accV[g][0][cc] += u0 * gev;
              accV[g][1][cc] += u1 * gev;
              accV[g][2][cc] += u2 * gev;
            }
          }
        }
      }
      __syncthreads();   // pass done before next plane overwrites P_lds
    }
  }

  // ---- final write: residual (br0) or accumulate (br1); no atomics ----
  #pragma unroll
  for (int g = 0; g < 2; g++) {
    int node = n0 + ty + 8 * g;
    if (node < N) {
      size_t os = (size_t)node * HD + c4;
      f32x4 vs = add_mode ? *(const f32x4*)&out_s[os] : *(const f32x4*)&ns[os];
      #pragma unroll
      for (int cc = 0; cc < 4; cc++) vs[cc] += accS[g][cc];
      *(f32x4*)&out_s[os] = vs;
      #pragma unroll
      for (int d = 0; d < 3; d++) {
        size_t ov = (size_t)node * 384 + (size_t)d * HD + c4;
        f32x4 vvv = add_mode ? *(const f32x4*)&out_v[ov] : *(const f32x4*)&nv[ov];
        #pragma unroll
        for (int cc = 0; cc < 4; cc++) vvv[cc] += accV[g][d][cc];
        *(f32x4*)&out_v[ov] = vvv;
      }
    }
  }
}

extern "C" void kernel_launch(void* const* d_in, const int* in_sizes, int n_in,
                              void* d_out, int out_size, void* d_ws, size_t ws_size,
                              hipStream_t stream)
{
  const float* node_scalar = (const float*)d_in[0];
  const float* node_vector = (const float*)d_in[1];
  const int*   che_edge = (const int*)d_in[2];
  const float* che_diff = (const float*)d_in[3];
  const float* che_dist = (const float*)d_in[4];
  const float* che_rbf  = (const float*)d_in[5];
  const int*   vdw_edge = (const int*)d_in[6];
  const float* vdw_diff = (const float*)d_in[7];
  const float* vdw_dist = (const float*)d_in[8];
  const float* vdw_rbf  = (const float*)d_in[9];
  const float* mlp_p[24];
  for (int i = 0; i < 24; i++) mlp_p[i] = (const float*)d_in[10 + i];
  // [che_s 0..5][che_f 6..11][vdw_s 12..17][vdw_f 18..23]

  const int N = in_sizes[0] / HD;
  const int E_che = in_sizes[4];
  const int E_vdw = in_sizes[8];
  const int E_max = E_che > E_vdw ? E_che : E_vdw;

  // workspace layout
  char* wp = (char*)d_ws;
  size_t off = 0;
  float* so       = (float*)(wp + off); off += (size_t)N * 384 * 4;
  int* counts     = (int*)(wp + off);   off += (size_t)N * 4;
  int* cursor     = (int*)(wp + off);   off += (size_t)N * 4;
  int* offsets    = (int*)(wp + off);   off += (size_t)(N + 1) * 4;
  off = (off + 255) & ~(size_t)255;
  int* edge_list  = (int*)(wp + off);   off += (size_t)E_max * 4;
  off = (off + 255) & ~(size_t)255;
  unsigned short* w2t_che = (unsigned short*)(wp + off); off += 384 * 128 * 2;
  unsigned short* w2t_vdw = (unsigned short*)(wp + off); off += 384 * 128 * 2;

  float* out_s = (float*)d_out;
  float* out_v = out_s + (size_t)N * HD;

  convert_w2_kernel<<<192, 256, 0, stream>>>(mlp_p[9], w2t_che, mlp_p[21], w2t_vdw);

  for (int br = 0; br < 2; br++) {
    const int*   edge = br == 0 ? che_edge : vdw_edge;
    const float* diff = br == 0 ? che_diff : vdw_diff;
    const float* dist = br == 0 ? che_dist : vdw_dist;
    const float* rbf  = br == 0 ? che_rbf  : vdw_rbf;
    const int    E    = br == 0 ? E_che : E_vdw;
    const float* const* sp = &mlp_p[br == 0 ? 0 : 12];
    const float* const* fp = &mlp_p[br == 0 ? 6 : 18];
    unsigned short* w2t = br == 0 ? w2t_che : w2t_vdw;

    node_mlp_kernel<<<(N + TM - 1) / TM, 256, 0, stream>>>(
        node_scalar, sp[0], sp[1], sp[2], sp[3], sp[4], sp[5], so, N);

    zero_int_kernel<<<(N + 255) / 256, 256, 0, stream>>>(counts, N);
    hist_kernel<<<(E + 255) / 256, 256, 0, stream>>>(edge, counts, E);
    scan_kernel<<<1, 1024, 0, stream>>>(counts, offsets, cursor, N);
    scatter_ids_kernel<<<(E + 255) / 256, 256, 0, stream>>>(edge, cursor, edge_list, E);

    edge_mfma_kernel<<<(N + NB - 1) / NB, 256, 0, stream>>>(
        so, node_scalar, node_vector, edge, diff, dist, rbf, edge_list, offsets,
        fp[0], fp[1], fp[2], w2t, fp[4], fp[5],
        out_s, out_v, N, br);
  }
}

// Round 5
// 1223.059 us; speedup vs baseline: 1.6079x; 1.5152x over previous
//
#include <hip/hip_runtime.h>

typedef float f32x4 __attribute__((ext_vector_type(4)));
typedef short bf16x8 __attribute__((ext_vector_type(8)));

#define HD 128

__device__ __forceinline__ float prelu_f(float x, float a) {
  return x > 0.f ? x : a * x;
}

__device__ __forceinline__ unsigned short f2bf(float x) {
  union { float f; unsigned u; } a; a.f = x;
  unsigned r = a.u + 0x7fffu + ((a.u >> 16) & 1u);
  return (unsigned short)(r >> 16);
}
__device__ __forceinline__ float bf2f(unsigned short u) {
  union { unsigned u; float f; } a; a.u = ((unsigned)u) << 16;
  return a.f;
}
__device__ __forceinline__ f32x4 bf4_to_f32(ushort4 u) {
  f32x4 r; r[0] = bf2f(u.x); r[1] = bf2f(u.y); r[2] = bf2f(u.z); r[3] = bf2f(u.w);
  return r;
}

// out = concat(node_scalar, node_vector)
__global__ __launch_bounds__(256) void init_out_kernel(
    const f32x4* __restrict__ ns, const f32x4* __restrict__ nv,
    f32x4* __restrict__ out, int n_ns4, int n_nv4)
{
  int total = n_ns4 + n_nv4;
  for (int i = blockIdx.x * 256 + threadIdx.x; i < total; i += gridDim.x * 256)
    out[i] = (i < n_ns4) ? ns[i] : nv[i - n_ns4];
}

// transpose+convert: src[128][384] f32 -> dst[384][128] bf16
__global__ __launch_bounds__(256) void tconv_kernel(
    const float* __restrict__ src, unsigned short* __restrict__ dst)
{
  int idx = blockIdx.x * 256 + threadIdx.x;
  if (idx < 384 * 128) {
    int c = idx >> 7, k = idx & 127;
    dst[idx] = f2bf(src[(size_t)k * 384 + c]);
  }
}

// ---------------- node MLP: layer1 fp32 VALU, layer2 bf16 MFMA ----------------
__global__ __launch_bounds__(256) void node_mlp_hybrid(
    const float* __restrict__ A,
    const float* __restrict__ w1, const float* __restrict__ b1, const float* __restrict__ a1p,
    const unsigned short* __restrict__ w2t,  // [384][128] bf16
    const float* __restrict__ b2, const float* __restrict__ a2p,
    float* __restrict__ out, int M)
{
  __shared__ float A_lds[64][HD];
  __shared__ __attribute__((aligned(16))) unsigned short h_lds[64 * HD];
  const int t = threadIdx.x;
  const int tx = t & 31, ty = t >> 5;
  const int c4 = tx * 4;
  const int wvid = t >> 6, lane = t & 63, l15 = lane & 15, l4 = lane >> 4;
  const int m0 = blockIdx.x * 64;
  const float a1 = a1p[0], a2 = a2p[0];

  for (int idx = t; idx < 64 * HD / 4; idx += 256) {
    int r = idx >> 5, cc = (idx & 31) * 4;
    f32x4 v = {0.f, 0.f, 0.f, 0.f};
    if (m0 + r < M) v = *(const f32x4*)&A[(size_t)(m0 + r) * HD + cc];
    *(f32x4*)&A_lds[r][cc] = v;
  }
  __syncthreads();

  // layer1 fp32 -> h bf16 (swizzled)
  {
    float acc[8][4];
    f32x4 bv = *(const f32x4*)&b1[c4];
    #pragma unroll
    for (int rr = 0; rr < 8; rr++)
      #pragma unroll
      for (int cc = 0; cc < 4; cc++) acc[rr][cc] = bv[cc];

    for (int kg = 0; kg < HD / 4; kg++) {
      const int k = kg * 4;
      f32x4 wv[4];
      #pragma unroll
      for (int kk = 0; kk < 4; kk++) wv[kk] = *(const f32x4*)&w1[(size_t)(k + kk) * HD + c4];
      #pragma unroll
      for (int rr = 0; rr < 8; rr++) {
        f32x4 av = *(const f32x4*)&A_lds[ty * 8 + rr][k];
        #pragma unroll
        for (int cc = 0; cc < 4; cc++)
          #pragma unroll
          for (int kk = 0; kk < 4; kk++)
            acc[rr][cc] += av[kk] * wv[kk][cc];
      }
    }
    #pragma unroll
    for (int rr = 0; rr < 8; rr++) {
      int row = ty * 8 + rr;
      ushort4 hp;
      hp.x = f2bf(prelu_f(acc[rr][0], a1));
      hp.y = f2bf(prelu_f(acc[rr][1], a1));
      hp.z = f2bf(prelu_f(acc[rr][2], a1));
      hp.w = f2bf(prelu_f(acc[rr][3], a1));
      *(ushort4*)&h_lds[row * HD + (c4 ^ ((row & 7) << 3))] = hp;
    }
  }
  __syncthreads();

  // layer2 MFMA: 3 plane groups of 128 cols
  for (int m = 0; m < 3; m++) {
    bf16x8 Bf[2][4];
    #pragma unroll
    for (int nf = 0; nf < 2; nf++)
      #pragma unroll
      for (int ks = 0; ks < 4; ks++) {
        int col = m * 128 + wvid * 32 + nf * 16 + l15;
        Bf[nf][ks] = *(const bf16x8*)&w2t[(size_t)col * 128 + ks * 32 + l4 * 8];
      }
    f32x4 D[4][2];
    #pragma unroll
    for (int mi = 0; mi < 4; mi++)
      #pragma unroll
      for (int nf = 0; nf < 2; nf++)
        #pragma unroll
        for (int cc = 0; cc < 4; cc++) D[mi][nf][cc] = 0.f;

    #pragma unroll
    for (int mi = 0; mi < 4; mi++)
      #pragma unroll
      for (int ks = 0; ks < 4; ks++) {
        int row = mi * 16 + l15;
        bf16x8 Af = *(const bf16x8*)&h_lds[row * HD + ((ks * 32 + l4 * 8) ^ ((row & 7) << 3))];
        D[mi][0] = __builtin_amdgcn_mfma_f32_16x16x32_bf16(Af, Bf[0][ks], D[mi][0], 0, 0, 0);
        D[mi][1] = __builtin_amdgcn_mfma_f32_16x16x32_bf16(Af, Bf[1][ks], D[mi][1], 0, 0, 0);
      }

    float b2v0 = b2[m * 128 + wvid * 32 + l15];
    float b2v1 = b2[m * 128 + wvid * 32 + 16 + l15];
    #pragma unroll
    for (int mi = 0; mi < 4; mi++)
      #pragma unroll
      for (int nf = 0; nf < 2; nf++)
        #pragma unroll
        for (int r4 = 0; r4 < 4; r4++) {
          int row = mi * 16 + l4 * 4 + r4;
          if (m0 + row < M) {
            int col = m * 128 + wvid * 32 + nf * 16 + l15;
            out[(size_t)(m0 + row) * 384 + col] = prelu_f(D[mi][nf][r4] + (nf ? b2v1 : b2v0), a2);
          }
        }
  }
}

// ---------------- CSR build ----------------
__global__ __launch_bounds__(256) void zero_int_kernel(int* __restrict__ p, int n) {
  int i = blockIdx.x * 256 + threadIdx.x;
  if (i < n) p[i] = 0;
}

__global__ __launch_bounds__(256) void hist_kernel(const int* __restrict__ edge, int* __restrict__ counts, int E) {
  int e = blockIdx.x * 256 + threadIdx.x;
  if (e < E) atomicAdd(&counts[edge[(size_t)e * 2]], 1);
}

__global__ __launch_bounds__(1024) void scan_kernel(
    const int* __restrict__ counts, int* __restrict__ offsets, int* __restrict__ cursor, int n)
{
  __shared__ int sums[1024];
  const int t = threadIdx.x;
  const int per = (n + 1023) / 1024;
  const int lo = t * per, hi = min(lo + per, n);
  int s = 0;
  for (int i = lo; i < hi; i++) s += counts[i];
  sums[t] = s;
  __syncthreads();
  for (int off = 1; off < 1024; off <<= 1) {
    int v = sums[t];
    int u = (t >= off) ? sums[t - off] : 0;
    __syncthreads();
    sums[t] = v + u;
    __syncthreads();
  }
  int run = (t == 0) ? 0 : sums[t - 1];
  for (int i = lo; i < hi; i++) {
    offsets[i] = run;
    cursor[i] = run;
    run += counts[i];
  }
  if (t == 1023) offsets[n] = sums[1023];
}

__global__ __launch_bounds__(256) void scatter_ids_kernel(
    const int* __restrict__ edge, int* __restrict__ cursor, int* __restrict__ edge_list, int E)
{
  int e = blockIdx.x * 256 + threadIdx.x;
  if (e < E) {
    int d = edge[(size_t)e * 2];
    int p = atomicAdd(&cursor[d], 1);
    edge_list[p] = e;
  }
}

// ---------------- edge kernel: filter MLP (layer2 MFMA) + gather + gate +
// bf16 msg store at dst-sorted position (no atomics) ----------------
__global__ __launch_bounds__(256) void edge_mfma_msg_kernel(
    const float* __restrict__ so,      // [N,384]
    const float* __restrict__ nv,      // [N,3,128]
    const int*   __restrict__ edge,    // [E,2] (dst, src)
    const float* __restrict__ diff,    // [E,3]
    const float* __restrict__ dist,    // [E]
    const float* __restrict__ rbf,     // [E,20]
    const int*   __restrict__ edge_list,
    const float* __restrict__ w1, const float* __restrict__ b1, const float* __restrict__ a1p,
    const unsigned short* __restrict__ w2t, // [384][128] bf16
    const float* __restrict__ b2, const float* __restrict__ a2p,
    unsigned short* __restrict__ msg,  // [chunk][512] bf16
    int p0, int p1)
{
  __shared__ float R_lds[64][20];
  __shared__ __attribute__((aligned(16))) unsigned short h_lds[64 * HD];
  __shared__ __attribute__((aligned(16))) unsigned short P_lds[3][64 * HD];
  __shared__ int eid_l[64], src_l[64];
  __shared__ float unit_l[64][3];

  const int t = threadIdx.x;
  const int tx = t & 31, ty = t >> 5;
  const int c4 = tx * 4;
  const int wvid = t >> 6, lane = t & 63, l15 = lane & 15, l4 = lane >> 4;
  const int pblk = p0 + blockIdx.x * 64;
  const float a1 = a1p[0], a2 = a2p[0];

  if (t < 64) {
    int p = pblk + t;
    if (p < p1) {
      int e = edge_list[p];
      eid_l[t] = e;
      src_l[t] = edge[(size_t)e * 2 + 1];
      float inv = 1.f / dist[e];
      unit_l[t][0] = diff[(size_t)e * 3 + 0] * inv;
      unit_l[t][1] = diff[(size_t)e * 3 + 1] * inv;
      unit_l[t][2] = diff[(size_t)e * 3 + 2] * inv;
    } else {
      eid_l[t] = -1; src_l[t] = 0;
      unit_l[t][0] = 0.f; unit_l[t][1] = 0.f; unit_l[t][2] = 0.f;
    }
  }
  __syncthreads();   // S1

  for (int idx = t; idx < 64 * 20; idx += 256) {
    int r = idx / 20, k = idx - r * 20;
    int e = eid_l[r];
    R_lds[r][k] = (e >= 0) ? rbf[(size_t)e * 20 + k] : 0.f;
  }
  __syncthreads();   // S2

  // layer1 (K=20, fp32) -> h bf16 swizzled
  {
    float ha[8][4];
    f32x4 bv = *(const f32x4*)&b1[c4];
    #pragma unroll
    for (int rr = 0; rr < 8; rr++)
      #pragma unroll
      for (int cc = 0; cc < 4; cc++) ha[rr][cc] = bv[cc];
    for (int k = 0; k < 20; k++) {
      f32x4 wvv = *(const f32x4*)&w1[(size_t)k * HD + c4];
      #pragma unroll
      for (int rr = 0; rr < 8; rr++) {
        float av = R_lds[ty * 8 + rr][k];
        #pragma unroll
        for (int cc = 0; cc < 4; cc++) ha[rr][cc] += av * wvv[cc];
      }
    }
    #pragma unroll
    for (int rr = 0; rr < 8; rr++) {
      int row = ty * 8 + rr;
      ushort4 hp;
      hp.x = f2bf(prelu_f(ha[rr][0], a1));
      hp.y = f2bf(prelu_f(ha[rr][1], a1));
      hp.z = f2bf(prelu_f(ha[rr][2], a1));
      hp.w = f2bf(prelu_f(ha[rr][3], a1));
      *(ushort4*)&h_lds[row * HD + (c4 ^ ((row & 7) << 3))] = hp;
    }
  }
  __syncthreads();   // S3

  // layer2 MFMA: 3 planes -> P_lds (each wave writes its own col range)
  for (int m = 0; m < 3; m++) {
    bf16x8 Bf[2][4];
    #pragma unroll
    for (int nf = 0; nf < 2; nf++)
      #pragma unroll
      for (int ks = 0; ks < 4; ks++) {
        int col = m * 128 + wvid * 32 + nf * 16 + l15;
        Bf[nf][ks] = *(const bf16x8*)&w2t[(size_t)col * 128 + ks * 32 + l4 * 8];
      }
    f32x4 D[4][2];
    #pragma unroll
    for (int mi = 0; mi < 4; mi++)
      #pragma unroll
      for (int nf = 0; nf < 2; nf++)
        #pragma unroll
        for (int cc = 0; cc < 4; cc++) D[mi][nf][cc] = 0.f;

    #pragma unroll
    for (int mi = 0; mi < 4; mi++)
      #pragma unroll
      for (int ks = 0; ks < 4; ks++) {
        int row = mi * 16 + l15;
        bf16x8 Af = *(const bf16x8*)&h_lds[row * HD + ((ks * 32 + l4 * 8) ^ ((row & 7) << 3))];
        D[mi][0] = __builtin_amdgcn_mfma_f32_16x16x32_bf16(Af, Bf[0][ks], D[mi][0], 0, 0, 0);
        D[mi][1] = __builtin_amdgcn_mfma_f32_16x16x32_bf16(Af, Bf[1][ks], D[mi][1], 0, 0, 0);
      }

    float b2v0 = b2[m * 128 + wvid * 32 + l15];
    float b2v1 = b2[m * 128 + wvid * 32 + 16 + l15];
    #pragma unroll
    for (int mi = 0; mi < 4; mi++)
      #pragma unroll
      for (int nf = 0; nf < 2; nf++)
        #pragma unroll
        for (int r4 = 0; r4 < 4; r4++) {
          int row = mi * 16 + l4 * 4 + r4;
          int col = wvid * 32 + nf * 16 + l15;
          float v = prelu_f(D[mi][nf][r4] + (nf ? b2v1 : b2v0), a2);
          P_lds[m][row * HD + (col ^ ((row & 7) << 3))] = f2bf(v);
        }
  }
  __syncthreads();   // S4

  // epilogue: gather + gate + bf16 msg store
  #pragma unroll
  for (int rr = 0; rr < 8; rr++) {
    const int r = ty * 8 + rr;
    const int p = pblk + r;
    if (p >= p1) continue;
    const int src = src_l[r];
    const int sc = c4 ^ ((r & 7) << 3);
    f32x4 gvp = bf4_to_f32(*(const ushort4*)&P_lds[0][r * HD + sc]);
    f32x4 msp = bf4_to_f32(*(const ushort4*)&P_lds[1][r * HD + sc]);
    f32x4 gep = bf4_to_f32(*(const ushort4*)&P_lds[2][r * HD + sc]);
    const size_t sb = (size_t)src * 384;
    f32x4 s0 = *(const f32x4*)&so[sb + c4];
    f32x4 s1 = *(const f32x4*)&so[sb + HD + c4];
    f32x4 s2 = *(const f32x4*)&so[sb + 2 * HD + c4];
    f32x4 v0 = *(const f32x4*)&nv[sb + c4];
    f32x4 v1 = *(const f32x4*)&nv[sb + HD + c4];
    f32x4 v2 = *(const f32x4*)&nv[sb + 2 * HD + c4];
    const float u0 = unit_l[r][0], u1 = unit_l[r][1], u2 = unit_l[r][2];
    f32x4 gv, ms, ge;
    #pragma unroll
    for (int cc = 0; cc < 4; cc++) {
      gv[cc] = gvp[cc] * s0[cc];
      ms[cc] = msp[cc] * s1[cc];
      ge[cc] = gep[cc] * s2[cc];
    }
    unsigned short* mrow = msg + (size_t)(p - p0) * 512;
    ushort4 pk;
    pk.x = f2bf(ms[0]); pk.y = f2bf(ms[1]); pk.z = f2bf(ms[2]); pk.w = f2bf(ms[3]);
    *(ushort4*)&mrow[c4] = pk;
    #pragma unroll
    for (int d = 0; d < 3; d++) {
      f32x4 vd = (d == 0) ? v0 : (d == 1) ? v1 : v2;
      const float ud = (d == 0) ? u0 : (d == 1) ? u1 : u2;
      f32x4 mv;
      #pragma unroll
      for (int cc = 0; cc < 4; cc++) mv[cc] = vd[cc] * gv[cc] + ud * ge[cc];
      ushort4 pv;
      pv.x = f2bf(mv[0]); pv.y = f2bf(mv[1]); pv.z = f2bf(mv[2]); pv.w = f2bf(mv[3]);
      *(ushort4*)&mrow[(1 + d) * HD + c4] = pv;
    }
  }
}

// ---------------- per-node segment sum of messages ----------------
__global__ __launch_bounds__(256) void gather_kernel(
    const unsigned short* __restrict__ msg,
    const int* __restrict__ offsets,
    float* __restrict__ out, int N, int p0, int p1)
{
  const int node = blockIdx.x * 2 + (threadIdx.x >> 7);
  if (node >= N) return;
  const int t = threadIdx.x & 127;
  int s = offsets[node], e = offsets[node + 1];
  s = max(s, p0); e = min(e, p1);
  if (s >= e) return;
  const int j = t * 4;
  f32x4 acc = {0.f, 0.f, 0.f, 0.f};
  for (int p = s; p < e; p++) {
    ushort4 u = *(const ushort4*)&msg[(size_t)(p - p0) * 512 + j];
    acc[0] += bf2f(u.x); acc[1] += bf2f(u.y);
    acc[2] += bf2f(u.z); acc[3] += bf2f(u.w);
  }
  size_t o = (j < 128) ? ((size_t)node * HD + j)
                       : ((size_t)N * HD + ((size_t)node * 3 + (j >> 7) - 1) * HD + (j & 127));
  f32x4 cur = *(f32x4*)&out[o];
  cur += acc;
  *(f32x4*)&out[o] = cur;
}

extern "C" void kernel_launch(void* const* d_in, const int* in_sizes, int n_in,
                              void* d_out, int out_size, void* d_ws, size_t ws_size,
                              hipStream_t stream)
{
  const float* node_scalar = (const float*)d_in[0];
  const float* node_vector = (const float*)d_in[1];
  const int*   che_edge = (const int*)d_in[2];
  const float* che_diff = (const float*)d_in[3];
  const float* che_dist = (const float*)d_in[4];
  const float* che_rbf  = (const float*)d_in[5];
  const int*   vdw_edge = (const int*)d_in[6];
  const float* vdw_diff = (const float*)d_in[7];
  const float* vdw_dist = (const float*)d_in[8];
  const float* vdw_rbf  = (const float*)d_in[9];
  const float* mlp_p[24];
  for (int i = 0; i < 24; i++) mlp_p[i] = (const float*)d_in[10 + i];
  // [che_s 0..5][che_f 6..11][vdw_s 12..17][vdw_f 18..23]

  const int N = in_sizes[0] / HD;
  const int E_che = in_sizes[4];
  const int E_vdw = in_sizes[8];
  const int E_max = E_che > E_vdw ? E_che : E_vdw;

  // workspace layout
  char* wp = (char*)d_ws;
  size_t off = 0;
  float* so       = (float*)(wp + off); off += (size_t)N * 384 * 4;
  int* counts     = (int*)(wp + off);   off += (size_t)N * 4;
  int* cursor     = (int*)(wp + off);   off += (size_t)N * 4;
  int* offsets    = (int*)(wp + off);   off += (size_t)(N + 1) * 4;
  off = (off + 255) & ~(size_t)255;
  int* edge_list  = (int*)(wp + off);   off += (size_t)E_max * 4;
  off = (off + 255) & ~(size_t)255;
  unsigned short* w2t_sche = (unsigned short*)(wp + off); off += 384 * 128 * 2;
  unsigned short* w2t_fche = (unsigned short*)(wp + off); off += 384 * 128 * 2;
  unsigned short* w2t_svdw = (unsigned short*)(wp + off); off += 384 * 128 * 2;
  unsigned short* w2t_fvdw = (unsigned short*)(wp + off); off += 384 * 128 * 2;
  off = (off + 255) & ~(size_t)255;
  unsigned short* msg = (unsigned short*)(wp + off);
  size_t cap_edges = (ws_size > off) ? (ws_size - off) / 1024 : 0;  // 512 bf16 per edge
  cap_edges &= ~(size_t)63;

  float* out_s = (float*)d_out;

  const int n_ns4 = N * HD / 4;
  const int n_nv4 = N * 3 * HD / 4;
  init_out_kernel<<<2048, 256, 0, stream>>>(
      (const f32x4*)node_scalar, (const f32x4*)node_vector, (f32x4*)d_out, n_ns4, n_nv4);

  tconv_kernel<<<192, 256, 0, stream>>>(mlp_p[3],  w2t_sche);
  tconv_kernel<<<192, 256, 0, stream>>>(mlp_p[9],  w2t_fche);
  tconv_kernel<<<192, 256, 0, stream>>>(mlp_p[15], w2t_svdw);
  tconv_kernel<<<192, 256, 0, stream>>>(mlp_p[21], w2t_fvdw);

  for (int br = 0; br < 2; br++) {
    const int*   edge = br == 0 ? che_edge : vdw_edge;
    const float* diff = br == 0 ? che_diff : vdw_diff;
    const float* dist = br == 0 ? che_dist : vdw_dist;
    const float* rbf  = br == 0 ? che_rbf  : vdw_rbf;
    const int    E    = br == 0 ? E_che : E_vdw;
    const float* const* sp = &mlp_p[br == 0 ? 0 : 12];
    const float* const* fp = &mlp_p[br == 0 ? 6 : 18];
    const unsigned short* w2t_s = br == 0 ? w2t_sche : w2t_svdw;
    const unsigned short* w2t_f = br == 0 ? w2t_fche : w2t_fvdw;

    node_mlp_hybrid<<<(N + 63) / 64, 256, 0, stream>>>(
        node_scalar, sp[0], sp[1], sp[2], w2t_s, sp[4], sp[5], so, N);

    zero_int_kernel<<<(N + 255) / 256, 256, 0, stream>>>(counts, N);
    hist_kernel<<<(E + 255) / 256, 256, 0, stream>>>(edge, counts, E);
    scan_kernel<<<1, 1024, 0, stream>>>(counts, offsets, cursor, N);
    scatter_ids_kernel<<<(E + 255) / 256, 256, 0, stream>>>(edge, cursor, edge_list, E);

    int cap = (int)(cap_edges > (size_t)E ? (size_t)E : cap_edges);
    if (cap < 64) cap = 64;
    for (int p0 = 0; p0 < E; p0 += cap) {
      int p1 = p0 + cap < E ? p0 + cap : E;
      int nblk = (p1 - p0 + 63) / 64;
      edge_mfma_msg_kernel<<<nblk, 256, 0, stream>>>(
          so, node_vector, edge, diff, dist, rbf, edge_list,
          fp[0], fp[1], fp[2], w2t_f, fp[4], fp[5], msg, p0, p1);
      gather_kernel<<<(N + 1) / 2, 256, 0, stream>>>(msg, offsets, (float*)d_out, N, p0, p1);
    }
  }
}

// Round 6
// 1205.151 us; speedup vs baseline: 1.6318x; 1.0149x over previous
//
#include <hip/hip_runtime.h>

typedef float f32x4 __attribute__((ext_vector_type(4)));
typedef short bf16x8 __attribute__((ext_vector_type(8)));

#define HD 128
#define CHUNK_EDGES 98304   // 96 MB msg ring -> L3-resident roundtrip

__device__ __forceinline__ float prelu_f(float x, float a) {
  return x > 0.f ? x : a * x;
}

__device__ __forceinline__ unsigned short f2bf(float x) {
  union { float f; unsigned u; } a; a.f = x;
  unsigned r = a.u + 0x7fffu + ((a.u >> 16) & 1u);
  return (unsigned short)(r >> 16);
}
__device__ __forceinline__ float bf2f(unsigned short u) {
  union { unsigned u; float f; } a; a.u = ((unsigned)u) << 16;
  return a.f;
}
__device__ __forceinline__ f32x4 bf4_to_f32(ushort4 u) {
  f32x4 r; r[0] = bf2f(u.x); r[1] = bf2f(u.y); r[2] = bf2f(u.z); r[3] = bf2f(u.w);
  return r;
}

// out = concat(node_scalar, node_vector)
__global__ __launch_bounds__(256) void init_out_kernel(
    const f32x4* __restrict__ ns, const f32x4* __restrict__ nv,
    f32x4* __restrict__ out, int n_ns4, int n_nv4)
{
  int total = n_ns4 + n_nv4;
  for (int i = blockIdx.x * 256 + threadIdx.x; i < total; i += gridDim.x * 256)
    out[i] = (i < n_ns4) ? ns[i] : nv[i - n_ns4];
}

// transpose+convert: src[128][384] f32 -> dst[384][128] bf16
__global__ __launch_bounds__(256) void tconv_kernel(
    const float* __restrict__ src, unsigned short* __restrict__ dst)
{
  int idx = blockIdx.x * 256 + threadIdx.x;
  if (idx < 384 * 128) {
    int c = idx >> 7, k = idx & 127;
    dst[idx] = f2bf(src[(size_t)k * 384 + c]);
  }
}

// f32 -> bf16 bulk convert (vectorized)
__global__ __launch_bounds__(256) void conv_bf16_kernel(
    const f32x4* __restrict__ src, ushort4* __restrict__ dst, int n4)
{
  int i = blockIdx.x * 256 + threadIdx.x;
  if (i < n4) {
    f32x4 v = src[i];
    ushort4 o;
    o.x = f2bf(v[0]); o.y = f2bf(v[1]); o.z = f2bf(v[2]); o.w = f2bf(v[3]);
    dst[i] = o;
  }
}

// ---------------- node MLP: layer1 fp32 VALU, layer2 bf16 MFMA, bf16 output ----------------
__global__ __launch_bounds__(256) void node_mlp_hybrid(
    const float* __restrict__ A,
    const float* __restrict__ w1, const float* __restrict__ b1, const float* __restrict__ a1p,
    const unsigned short* __restrict__ w2t,  // [384][128] bf16
    const float* __restrict__ b2, const float* __restrict__ a2p,
    unsigned short* __restrict__ out,        // [M,384] bf16
    int M)
{
  __shared__ float A_lds[64][HD];
  __shared__ __attribute__((aligned(16))) unsigned short h_lds[64 * HD];
  const int t = threadIdx.x;
  const int tx = t & 31, ty = t >> 5;
  const int c4 = tx * 4;
  const int wvid = t >> 6, lane = t & 63, l15 = lane & 15, l4 = lane >> 4;
  const int m0 = blockIdx.x * 64;
  const float a1 = a1p[0], a2 = a2p[0];

  for (int idx = t; idx < 64 * HD / 4; idx += 256) {
    int r = idx >> 5, cc = (idx & 31) * 4;
    f32x4 v = {0.f, 0.f, 0.f, 0.f};
    if (m0 + r < M) v = *(const f32x4*)&A[(size_t)(m0 + r) * HD + cc];
    *(f32x4*)&A_lds[r][cc] = v;
  }
  __syncthreads();

  // layer1 fp32 -> h bf16 (swizzled)
  {
    float acc[8][4];
    f32x4 bv = *(const f32x4*)&b1[c4];
    #pragma unroll
    for (int rr = 0; rr < 8; rr++)
      #pragma unroll
      for (int cc = 0; cc < 4; cc++) acc[rr][cc] = bv[cc];

    for (int kg = 0; kg < HD / 4; kg++) {
      const int k = kg * 4;
      f32x4 wv[4];
      #pragma unroll
      for (int kk = 0; kk < 4; kk++) wv[kk] = *(const f32x4*)&w1[(size_t)(k + kk) * HD + c4];
      #pragma unroll
      for (int rr = 0; rr < 8; rr++) {
        f32x4 av = *(const f32x4*)&A_lds[ty * 8 + rr][k];
        #pragma unroll
        for (int cc = 0; cc < 4; cc++)
          #pragma unroll
          for (int kk = 0; kk < 4; kk++)
            acc[rr][cc] += av[kk] * wv[kk][cc];
      }
    }
    #pragma unroll
    for (int rr = 0; rr < 8; rr++) {
      int row = ty * 8 + rr;
      ushort4 hp;
      hp.x = f2bf(prelu_f(acc[rr][0], a1));
      hp.y = f2bf(prelu_f(acc[rr][1], a1));
      hp.z = f2bf(prelu_f(acc[rr][2], a1));
      hp.w = f2bf(prelu_f(acc[rr][3], a1));
      *(ushort4*)&h_lds[row * HD + (c4 ^ ((row & 7) << 3))] = hp;
    }
  }
  __syncthreads();

  // layer2 MFMA: 3 plane groups of 128 cols
  for (int m = 0; m < 3; m++) {
    bf16x8 Bf[2][4];
    #pragma unroll
    for (int nf = 0; nf < 2; nf++)
      #pragma unroll
      for (int ks = 0; ks < 4; ks++) {
        int col = m * 128 + wvid * 32 + nf * 16 + l15;
        Bf[nf][ks] = *(const bf16x8*)&w2t[(size_t)col * 128 + ks * 32 + l4 * 8];
      }
    f32x4 D[4][2];
    #pragma unroll
    for (int mi = 0; mi < 4; mi++)
      #pragma unroll
      for (int nf = 0; nf < 2; nf++)
        #pragma unroll
        for (int cc = 0; cc < 4; cc++) D[mi][nf][cc] = 0.f;

    #pragma unroll
    for (int mi = 0; mi < 4; mi++)
      #pragma unroll
      for (int ks = 0; ks < 4; ks++) {
        int row = mi * 16 + l15;
        bf16x8 Af = *(const bf16x8*)&h_lds[row * HD + ((ks * 32 + l4 * 8) ^ ((row & 7) << 3))];
        D[mi][0] = __builtin_amdgcn_mfma_f32_16x16x32_bf16(Af, Bf[0][ks], D[mi][0], 0, 0, 0);
        D[mi][1] = __builtin_amdgcn_mfma_f32_16x16x32_bf16(Af, Bf[1][ks], D[mi][1], 0, 0, 0);
      }

    float b2v0 = b2[m * 128 + wvid * 32 + l15];
    float b2v1 = b2[m * 128 + wvid * 32 + 16 + l15];
    #pragma unroll
    for (int mi = 0; mi < 4; mi++)
      #pragma unroll
      for (int nf = 0; nf < 2; nf++)
        #pragma unroll
        for (int r4 = 0; r4 < 4; r4++) {
          int row = mi * 16 + l4 * 4 + r4;
          if (m0 + row < M) {
            int col = m * 128 + wvid * 32 + nf * 16 + l15;
            out[(size_t)(m0 + row) * 384 + col] =
                f2bf(prelu_f(D[mi][nf][r4] + (nf ? b2v1 : b2v0), a2));
          }
        }
  }
}

// ---------------- CSR build ----------------
__global__ __launch_bounds__(256) void zero_int_kernel(int* __restrict__ p, int n) {
  int i = blockIdx.x * 256 + threadIdx.x;
  if (i < n) p[i] = 0;
}

__global__ __launch_bounds__(256) void hist_kernel(const int* __restrict__ edge, int* __restrict__ counts, int E) {
  int e = blockIdx.x * 256 + threadIdx.x;
  if (e < E) atomicAdd(&counts[edge[(size_t)e * 2]], 1);
}

__global__ __launch_bounds__(1024) void scan_kernel(
    const int* __restrict__ counts, int* __restrict__ offsets, int* __restrict__ cursor, int n)
{
  __shared__ int sums[1024];
  const int t = threadIdx.x;
  const int per = (n + 1023) / 1024;
  const int lo = t * per, hi = min(lo + per, n);
  int s = 0;
  for (int i = lo; i < hi; i++) s += counts[i];
  sums[t] = s;
  __syncthreads();
  for (int off = 1; off < 1024; off <<= 1) {
    int v = sums[t];
    int u = (t >= off) ? sums[t - off] : 0;
    __syncthreads();
    sums[t] = v + u;
    __syncthreads();
  }
  int run = (t == 0) ? 0 : sums[t - 1];
  for (int i = lo; i < hi; i++) {
    offsets[i] = run;
    cursor[i] = run;
    run += counts[i];
  }
  if (t == 1023) offsets[n] = sums[1023];
}

__global__ __launch_bounds__(256) void scatter_ids_kernel(
    const int* __restrict__ edge, int* __restrict__ cursor, int* __restrict__ edge_list, int E)
{
  int e = blockIdx.x * 256 + threadIdx.x;
  if (e < E) {
    int d = edge[(size_t)e * 2];
    int p = atomicAdd(&cursor[d], 1);
    edge_list[p] = e;
  }
}

// ---------------- edge kernel: filter MLP (layer2 MFMA) + bf16 gather + gate +
// bf16 msg store at dst-sorted position (no atomics) ----------------
__global__ __launch_bounds__(256) void edge_mfma_msg_kernel(
    const unsigned short* __restrict__ so,  // [N,384] bf16
    const unsigned short* __restrict__ nv,  // [N,3,128] bf16
    const int*   __restrict__ edge,    // [E,2] (dst, src)
    const float* __restrict__ diff,    // [E,3]
    const float* __restrict__ dist,    // [E]
    const float* __restrict__ rbf,     // [E,20]
    const int*   __restrict__ edge_list,
    const float* __restrict__ w1, const float* __restrict__ b1, const float* __restrict__ a1p,
    const unsigned short* __restrict__ w2t, // [384][128] bf16
    const float* __restrict__ b2, const float* __restrict__ a2p,
    unsigned short* __restrict__ msg,  // [chunk][512] bf16
    int p0, int p1)
{
  __shared__ float R_lds[64][20];
  __shared__ __attribute__((aligned(16))) unsigned short h_lds[64 * HD];
  __shared__ __attribute__((aligned(16))) unsigned short P_lds[3][64 * HD];
  __shared__ int eid_l[64], src_l[64];
  __shared__ float unit_l[64][3];

  const int t = threadIdx.x;
  const int tx = t & 31, ty = t >> 5;
  const int c4 = tx * 4;
  const int wvid = t >> 6, lane = t & 63, l15 = lane & 15, l4 = lane >> 4;
  const int pblk = p0 + blockIdx.x * 64;
  const float a1 = a1p[0], a2 = a2p[0];

  if (t < 64) {
    int p = pblk + t;
    if (p < p1) {
      int e = edge_list[p];
      eid_l[t] = e;
      src_l[t] = edge[(size_t)e * 2 + 1];
      float inv = 1.f / dist[e];
      unit_l[t][0] = diff[(size_t)e * 3 + 0] * inv;
      unit_l[t][1] = diff[(size_t)e * 3 + 1] * inv;
      unit_l[t][2] = diff[(size_t)e * 3 + 2] * inv;
    } else {
      eid_l[t] = -1; src_l[t] = 0;
      unit_l[t][0] = 0.f; unit_l[t][1] = 0.f; unit_l[t][2] = 0.f;
    }
  }
  __syncthreads();   // S1

  for (int idx = t; idx < 64 * 20; idx += 256) {
    int r = idx / 20, k = idx - r * 20;
    int e = eid_l[r];
    R_lds[r][k] = (e >= 0) ? rbf[(size_t)e * 20 + k] : 0.f;
  }
  __syncthreads();   // S2

  // layer1 (K=20, fp32) -> h bf16 swizzled
  {
    float ha[8][4];
    f32x4 bv = *(const f32x4*)&b1[c4];
    #pragma unroll
    for (int rr = 0; rr < 8; rr++)
      #pragma unroll
      for (int cc = 0; cc < 4; cc++) ha[rr][cc] = bv[cc];
    for (int k = 0; k < 20; k++) {
      f32x4 wvv = *(const f32x4*)&w1[(size_t)k * HD + c4];
      #pragma unroll
      for (int rr = 0; rr < 8; rr++) {
        float av = R_lds[ty * 8 + rr][k];
        #pragma unroll
        for (int cc = 0; cc < 4; cc++) ha[rr][cc] += av * wvv[cc];
      }
    }
    #pragma unroll
    for (int rr = 0; rr < 8; rr++) {
      int row = ty * 8 + rr;
      ushort4 hp;
      hp.x = f2bf(prelu_f(ha[rr][0], a1));
      hp.y = f2bf(prelu_f(ha[rr][1], a1));
      hp.z = f2bf(prelu_f(ha[rr][2], a1));
      hp.w = f2bf(prelu_f(ha[rr][3], a1));
      *(ushort4*)&h_lds[row * HD + (c4 ^ ((row & 7) << 3))] = hp;
    }
  }
  __syncthreads();   // S3

  // layer2 MFMA: 3 planes -> P_lds
  for (int m = 0; m < 3; m++) {
    bf16x8 Bf[2][4];
    #pragma unroll
    for (int nf = 0; nf < 2; nf++)
      #pragma unroll
      for (int ks = 0; ks < 4; ks++) {
        int col = m * 128 + wvid * 32 + nf * 16 + l15;
        Bf[nf][ks] = *(const bf16x8*)&w2t[(size_t)col * 128 + ks * 32 + l4 * 8];
      }
    f32x4 D[4][2];
    #pragma unroll
    for (int mi = 0; mi < 4; mi++)
      #pragma unroll
      for (int nf = 0; nf < 2; nf++)
        #pragma unroll
        for (int cc = 0; cc < 4; cc++) D[mi][nf][cc] = 0.f;

    #pragma unroll
    for (int mi = 0; mi < 4; mi++)
      #pragma unroll
      for (int ks = 0; ks < 4; ks++) {
        int row = mi * 16 + l15;
        bf16x8 Af = *(const bf16x8*)&h_lds[row * HD + ((ks * 32 + l4 * 8) ^ ((row & 7) << 3))];
        D[mi][0] = __builtin_amdgcn_mfma_f32_16x16x32_bf16(Af, Bf[0][ks], D[mi][0], 0, 0, 0);
        D[mi][1] = __builtin_amdgcn_mfma_f32_16x16x32_bf16(Af, Bf[1][ks], D[mi][1], 0, 0, 0);
      }

    float b2v0 = b2[m * 128 + wvid * 32 + l15];
    float b2v1 = b2[m * 128 + wvid * 32 + 16 + l15];
    #pragma unroll
    for (int mi = 0; mi < 4; mi++)
      #pragma unroll
      for (int nf = 0; nf < 2; nf++)
        #pragma unroll
        for (int r4 = 0; r4 < 4; r4++) {
          int row = mi * 16 + l4 * 4 + r4;
          int col = wvid * 32 + nf * 16 + l15;
          float v = prelu_f(D[mi][nf][r4] + (nf ? b2v1 : b2v0), a2);
          P_lds[m][row * HD + (col ^ ((row & 7) << 3))] = f2bf(v);
        }
  }
  __syncthreads();   // S4

  // epilogue: bf16 gather + gate + bf16 msg store
  #pragma unroll
  for (int rr = 0; rr < 8; rr++) {
    const int r = ty * 8 + rr;
    const int p = pblk + r;
    if (p >= p1) continue;
    const int src = src_l[r];
    const int sc = c4 ^ ((r & 7) << 3);
    f32x4 gvp = bf4_to_f32(*(const ushort4*)&P_lds[0][r * HD + sc]);
    f32x4 msp = bf4_to_f32(*(const ushort4*)&P_lds[1][r * HD + sc]);
    f32x4 gep = bf4_to_f32(*(const ushort4*)&P_lds[2][r * HD + sc]);
    const size_t sb = (size_t)src * 384;
    f32x4 s0 = bf4_to_f32(*(const ushort4*)&so[sb + c4]);
    f32x4 s1 = bf4_to_f32(*(const ushort4*)&so[sb + HD + c4]);
    f32x4 s2 = bf4_to_f32(*(const ushort4*)&so[sb + 2 * HD + c4]);
    f32x4 v0 = bf4_to_f32(*(const ushort4*)&nv[sb + c4]);
    f32x4 v1 = bf4_to_f32(*(const ushort4*)&nv[sb + HD + c4]);
    f32x4 v2 = bf4_to_f32(*(const ushort4*)&nv[sb + 2 * HD + c4]);
    const float u0 = unit_l[r][0], u1 = unit_l[r][1], u2 = unit_l[r][2];
    f32x4 gv, ms, ge;
    #pragma unroll
    for (int cc = 0; cc < 4; cc++) {
      gv[cc] = gvp[cc] * s0[cc];
      ms[cc] = msp[cc] * s1[cc];
      ge[cc] = gep[cc] * s2[cc];
    }
    unsigned short* mrow = msg + (size_t)(p - p0) * 512;
    ushort4 pk;
    pk.x = f2bf(ms[0]); pk.y = f2bf(ms[1]); pk.z = f2bf(ms[2]); pk.w = f2bf(ms[3]);
    *(ushort4*)&mrow[c4] = pk;
    #pragma unroll
    for (int d = 0; d < 3; d++) {
      f32x4 vd = (d == 0) ? v0 : (d == 1) ? v1 : v2;
      const float ud = (d == 0) ? u0 : (d == 1) ? u1 : u2;
      f32x4 mv;
      #pragma unroll
      for (int cc = 0; cc < 4; cc++) mv[cc] = vd[cc] * gv[cc] + ud * ge[cc];
      ushort4 pv;
      pv.x = f2bf(mv[0]); pv.y = f2bf(mv[1]); pv.z = f2bf(mv[2]); pv.w = f2bf(mv[3]);
      *(ushort4*)&mrow[(1 + d) * HD + c4] = pv;
    }
  }
}

// ---------------- per-node segment sum of messages ----------------
__global__ __launch_bounds__(256) void gather_kernel(
    const unsigned short* __restrict__ msg,
    const int* __restrict__ offsets,
    float* __restrict__ out, int N, int p0, int p1)
{
  const int node = blockIdx.x * 2 + (threadIdx.x >> 7);
  if (node >= N) return;
  const int t = threadIdx.x & 127;
  int s = offsets[node], e = offsets[node + 1];
  s = max(s, p0); e = min(e, p1);
  if (s >= e) return;
  const int j = t * 4;
  f32x4 acc = {0.f, 0.f, 0.f, 0.f};
  for (int p = s; p < e; p++) {
    ushort4 u = *(const ushort4*)&msg[(size_t)(p - p0) * 512 + j];
    acc[0] += bf2f(u.x); acc[1] += bf2f(u.y);
    acc[2] += bf2f(u.z); acc[3] += bf2f(u.w);
  }
  size_t o = (j < 128) ? ((size_t)node * HD + j)
                       : ((size_t)N * HD + ((size_t)node * 3 + (j >> 7) - 1) * HD + (j & 127));
  f32x4 cur = *(f32x4*)&out[o];
  cur += acc;
  *(f32x4*)&out[o] = cur;
}

extern "C" void kernel_launch(void* const* d_in, const int* in_sizes, int n_in,
                              void* d_out, int out_size, void* d_ws, size_t ws_size,
                              hipStream_t stream)
{
  const float* node_scalar = (const float*)d_in[0];
  const float* node_vector = (const float*)d_in[1];
  const int*   che_edge = (const int*)d_in[2];
  const float* che_diff = (const float*)d_in[3];
  const float* che_dist = (const float*)d_in[4];
  const float* che_rbf  = (const float*)d_in[5];
  const int*   vdw_edge = (const int*)d_in[6];
  const float* vdw_diff = (const float*)d_in[7];
  const float* vdw_dist = (const float*)d_in[8];
  const float* vdw_rbf  = (const float*)d_in[9];
  const float* mlp_p[24];
  for (int i = 0; i < 24; i++) mlp_p[i] = (const float*)d_in[10 + i];
  // [che_s 0..5][che_f 6..11][vdw_s 12..17][vdw_f 18..23]

  const int N = in_sizes[0] / HD;
  const int E_che = in_sizes[4];
  const int E_vdw = in_sizes[8];
  const int E_max = E_che > E_vdw ? E_che : E_vdw;

  // workspace layout
  char* wp = (char*)d_ws;
  size_t off = 0;
  unsigned short* so_bf = (unsigned short*)(wp + off); off += (size_t)N * 384 * 2;
  unsigned short* nv_bf = (unsigned short*)(wp + off); off += (size_t)N * 384 * 2;
  int* counts     = (int*)(wp + off);   off += (size_t)N * 4;
  int* cursor     = (int*)(wp + off);   off += (size_t)N * 4;
  int* offsets    = (int*)(wp + off);   off += (size_t)(N + 1) * 4;
  off = (off + 255) & ~(size_t)255;
  int* edge_list  = (int*)(wp + off);   off += (size_t)E_max * 4;
  off = (off + 255) & ~(size_t)255;
  unsigned short* w2t_sche = (unsigned short*)(wp + off); off += 384 * 128 * 2;
  unsigned short* w2t_fche = (unsigned short*)(wp + off); off += 384 * 128 * 2;
  unsigned short* w2t_svdw = (unsigned short*)(wp + off); off += 384 * 128 * 2;
  unsigned short* w2t_fvdw = (unsigned short*)(wp + off); off += 384 * 128 * 2;
  off = (off + 255) & ~(size_t)255;
  unsigned short* msg = (unsigned short*)(wp + off);
  size_t cap_edges = (ws_size > off) ? (ws_size - off) / 1024 : 0;  // 512 bf16 per edge
  cap_edges &= ~(size_t)63;
  if (cap_edges > CHUNK_EDGES) cap_edges = CHUNK_EDGES;

  const int n_ns4 = N * HD / 4;
  const int n_nv4 = N * 3 * HD / 4;
  init_out_kernel<<<2048, 256, 0, stream>>>(
      (const f32x4*)node_scalar, (const f32x4*)node_vector, (f32x4*)d_out, n_ns4, n_nv4);

  conv_bf16_kernel<<<(n_nv4 + 255) / 256, 256, 0, stream>>>(
      (const f32x4*)node_vector, (ushort4*)nv_bf, n_nv4);

  tconv_kernel<<<192, 256, 0, stream>>>(mlp_p[3],  w2t_sche);
  tconv_kernel<<<192, 256, 0, stream>>>(mlp_p[9],  w2t_fche);
  tconv_kernel<<<192, 256, 0, stream>>>(mlp_p[15], w2t_svdw);
  tconv_kernel<<<192, 256, 0, stream>>>(mlp_p[21], w2t_fvdw);

  for (int br = 0; br < 2; br++) {
    const int*   edge = br == 0 ? che_edge : vdw_edge;
    const float* diff = br == 0 ? che_diff : vdw_diff;
    const float* dist = br == 0 ? che_dist : vdw_dist;
    const float* rbf  = br == 0 ? che_rbf  : vdw_rbf;
    const int    E    = br == 0 ? E_che : E_vdw;
    const float* const* sp = &mlp_p[br == 0 ? 0 : 12];
    const float* const* fp = &mlp_p[br == 0 ? 6 : 18];
    const unsigned short* w2t_s = br == 0 ? w2t_sche : w2t_svdw;
    const unsigned short* w2t_f = br == 0 ? w2t_fche : w2t_fvdw;

    node_mlp_hybrid<<<(N + 63) / 64, 256, 0, stream>>>(
        node_scalar, sp[0], sp[1], sp[2], w2t_s, sp[4], sp[5], so_bf, N);

    zero_int_kernel<<<(N + 255) / 256, 256, 0, stream>>>(counts, N);
    hist_kernel<<<(E + 255) / 256, 256, 0, stream>>>(edge, counts, E);
    scan_kernel<<<1, 1024, 0, stream>>>(counts, offsets, cursor, N);
    scatter_ids_kernel<<<(E + 255) / 256, 256, 0, stream>>>(edge, cursor, edge_list, E);

    int cap = (int)(cap_edges > (size_t)E ? (size_t)E : cap_edges);
    if (cap < 64) cap = 64;
    for (int p0 = 0; p0 < E; p0 += cap) {
      int p1 = p0 + cap < E ? p0 + cap : E;
      int nblk = (p1 - p0 + 63) / 64;
      edge_mfma_msg_kernel<<<nblk, 256, 0, stream>>>(
          so_bf, nv_bf, edge, diff, dist, rbf, edge_list,
          fp[0], fp[1], fp[2], w2t_f, fp[4], fp[5], msg, p0, p1);
      gather_kernel<<<(N + 1) / 2, 256, 0, stream>>>(msg, offsets, (float*)d_out, N, p0, p1);
    }
  }
}

// Round 7
// 1002.569 us; speedup vs baseline: 1.9615x; 1.2021x over previous
//
#include <hip/hip_runtime.h>

typedef float f32x4 __attribute__((ext_vector_type(4)));
typedef short bf16x8 __attribute__((ext_vector_type(8)));

#define HD 128
#define CHUNK_EDGES 98304   // 96 MB msg ring -> L3-resident roundtrip
#define SCAN_TILE 2048      // counts per scan block (256 thr x 8)

__device__ __forceinline__ float prelu_f(float x, float a) {
  return x > 0.f ? x : a * x;
}

__device__ __forceinline__ unsigned short f2bf(float x) {
  union { float f; unsigned u; } a; a.f = x;
  unsigned r = a.u + 0x7fffu + ((a.u >> 16) & 1u);
  return (unsigned short)(r >> 16);
}
__device__ __forceinline__ float bf2f(unsigned short u) {
  union { unsigned u; float f; } a; a.u = ((unsigned)u) << 16;
  return a.f;
}
__device__ __forceinline__ f32x4 bf4_to_f32(ushort4 u) {
  f32x4 r; r[0] = bf2f(u.x); r[1] = bf2f(u.y); r[2] = bf2f(u.z); r[3] = bf2f(u.w);
  return r;
}

// transpose+convert: src[128][384] f32 -> dst[384][128] bf16
__global__ __launch_bounds__(256) void tconv_kernel(
    const float* __restrict__ src, unsigned short* __restrict__ dst)
{
  int idx = blockIdx.x * 256 + threadIdx.x;
  if (idx < 384 * 128) {
    int c = idx >> 7, k = idx & 127;
    dst[idx] = f2bf(src[(size_t)k * 384 + c]);
  }
}

// f32 -> bf16 bulk convert (vectorized)
__global__ __launch_bounds__(256) void conv_bf16_kernel(
    const f32x4* __restrict__ src, ushort4* __restrict__ dst, int n4)
{
  int i = blockIdx.x * 256 + threadIdx.x;
  if (i < n4) {
    f32x4 v = src[i];
    ushort4 o;
    o.x = f2bf(v[0]); o.y = f2bf(v[1]); o.z = f2bf(v[2]); o.w = f2bf(v[3]);
    dst[i] = o;
  }
}

// ---------------- node MLP: layer1 fp32 VALU, layer2 bf16 MFMA, bf16 output ----------------
__global__ __launch_bounds__(256) void node_mlp_hybrid(
    const float* __restrict__ A,
    const float* __restrict__ w1, const float* __restrict__ b1, const float* __restrict__ a1p,
    const unsigned short* __restrict__ w2t,  // [384][128] bf16
    const float* __restrict__ b2, const float* __restrict__ a2p,
    unsigned short* __restrict__ out,        // [M,384] bf16
    int M)
{
  __shared__ float A_lds[64][HD];
  __shared__ __attribute__((aligned(16))) unsigned short h_lds[64 * HD];
  const int t = threadIdx.x;
  const int tx = t & 31, ty = t >> 5;
  const int c4 = tx * 4;
  const int wvid = t >> 6, lane = t & 63, l15 = lane & 15, l4 = lane >> 4;
  const int m0 = blockIdx.x * 64;
  const float a1 = a1p[0], a2 = a2p[0];

  for (int idx = t; idx < 64 * HD / 4; idx += 256) {
    int r = idx >> 5, cc = (idx & 31) * 4;
    f32x4 v = {0.f, 0.f, 0.f, 0.f};
    if (m0 + r < M) v = *(const f32x4*)&A[(size_t)(m0 + r) * HD + cc];
    *(f32x4*)&A_lds[r][cc] = v;
  }
  __syncthreads();

  // layer1 fp32 -> h bf16 (swizzled)
  {
    float acc[8][4];
    f32x4 bv = *(const f32x4*)&b1[c4];
    #pragma unroll
    for (int rr = 0; rr < 8; rr++)
      #pragma unroll
      for (int cc = 0; cc < 4; cc++) acc[rr][cc] = bv[cc];

    for (int kg = 0; kg < HD / 4; kg++) {
      const int k = kg * 4;
      f32x4 wv[4];
      #pragma unroll
      for (int kk = 0; kk < 4; kk++) wv[kk] = *(const f32x4*)&w1[(size_t)(k + kk) * HD + c4];
      #pragma unroll
      for (int rr = 0; rr < 8; rr++) {
        f32x4 av = *(const f32x4*)&A_lds[ty * 8 + rr][k];
        #pragma unroll
        for (int cc = 0; cc < 4; cc++)
          #pragma unroll
          for (int kk = 0; kk < 4; kk++)
            acc[rr][cc] += av[kk] * wv[kk][cc];
      }
    }
    #pragma unroll
    for (int rr = 0; rr < 8; rr++) {
      int row = ty * 8 + rr;
      ushort4 hp;
      hp.x = f2bf(prelu_f(acc[rr][0], a1));
      hp.y = f2bf(prelu_f(acc[rr][1], a1));
      hp.z = f2bf(prelu_f(acc[rr][2], a1));
      hp.w = f2bf(prelu_f(acc[rr][3], a1));
      *(ushort4*)&h_lds[row * HD + (c4 ^ ((row & 7) << 3))] = hp;
    }
  }
  __syncthreads();

  // layer2 MFMA: 3 plane groups of 128 cols
  for (int m = 0; m < 3; m++) {
    bf16x8 Bf[2][4];
    #pragma unroll
    for (int nf = 0; nf < 2; nf++)
      #pragma unroll
      for (int ks = 0; ks < 4; ks++) {
        int col = m * 128 + wvid * 32 + nf * 16 + l15;
        Bf[nf][ks] = *(const bf16x8*)&w2t[(size_t)col * 128 + ks * 32 + l4 * 8];
      }
    f32x4 D[4][2];
    #pragma unroll
    for (int mi = 0; mi < 4; mi++)
      #pragma unroll
      for (int nf = 0; nf < 2; nf++)
        #pragma unroll
        for (int cc = 0; cc < 4; cc++) D[mi][nf][cc] = 0.f;

    #pragma unroll
    for (int mi = 0; mi < 4; mi++)
      #pragma unroll
      for (int ks = 0; ks < 4; ks++) {
        int row = mi * 16 + l15;
        bf16x8 Af = *(const bf16x8*)&h_lds[row * HD + ((ks * 32 + l4 * 8) ^ ((row & 7) << 3))];
        D[mi][0] = __builtin_amdgcn_mfma_f32_16x16x32_bf16(Af, Bf[0][ks], D[mi][0], 0, 0, 0);
        D[mi][1] = __builtin_amdgcn_mfma_f32_16x16x32_bf16(Af, Bf[1][ks], D[mi][1], 0, 0, 0);
      }

    float b2v0 = b2[m * 128 + wvid * 32 + l15];
    float b2v1 = b2[m * 128 + wvid * 32 + 16 + l15];
    #pragma unroll
    for (int mi = 0; mi < 4; mi++)
      #pragma unroll
      for (int nf = 0; nf < 2; nf++)
        #pragma unroll
        for (int r4 = 0; r4 < 4; r4++) {
          int row = mi * 16 + l4 * 4 + r4;
          if (m0 + row < M) {
            int col = m * 128 + wvid * 32 + nf * 16 + l15;
            out[(size_t)(m0 + row) * 384 + col] =
                f2bf(prelu_f(D[mi][nf][r4] + (nf ? b2v1 : b2v0), a2));
          }
        }
  }
}

// ---------------- CSR build ----------------
__global__ __launch_bounds__(256) void zero_int_kernel(int* __restrict__ p, int n) {
  int i = blockIdx.x * 256 + threadIdx.x;
  if (i < n) p[i] = 0;
}

__global__ __launch_bounds__(256) void hist_kernel(const int* __restrict__ edge, int* __restrict__ counts, int E) {
  int e = blockIdx.x * 256 + threadIdx.x;
  if (e < E) atomicAdd(&counts[edge[(size_t)e * 2]], 1);
}

// phase 1: per-block partial sums over SCAN_TILE counts
__global__ __launch_bounds__(256) void scan_partial_kernel(
    const int* __restrict__ counts, int* __restrict__ partials, int n)
{
  const int b = blockIdx.x, t = threadIdx.x;
  const int base = b * SCAN_TILE + t * 8;
  int s = 0;
  #pragma unroll
  for (int i = 0; i < 8; i++) {
    int idx = base + i;
    if (idx < n) s += counts[idx];
  }
  __shared__ int sums[256];
  sums[t] = s;
  __syncthreads();
  for (int o = 128; o > 0; o >>= 1) {
    if (t < o) sums[t] += sums[t + o];
    __syncthreads();
  }
  if (t == 0) partials[b] = sums[0];
}

// phase 2: single-block exclusive scan of block partials (nb <= 256)
__global__ __launch_bounds__(256) void scan_partials_kernel(int* __restrict__ partials, int nb)
{
  __shared__ int s[256];
  const int t = threadIdx.x;
  s[t] = (t < nb) ? partials[t] : 0;
  __syncthreads();
  for (int o = 1; o < 256; o <<= 1) {
    int v = s[t];
    int u = (t >= o) ? s[t - o] : 0;
    __syncthreads();
    s[t] = v + u;
    __syncthreads();
  }
  if (t < nb) partials[t] = (t == 0) ? 0 : s[t - 1];
}

// phase 3: per-block local scan + write offsets/cursor
__global__ __launch_bounds__(256) void scan_write_kernel(
    const int* __restrict__ counts, const int* __restrict__ partials,
    int* __restrict__ offsets, int* __restrict__ cursor, int n, int E)
{
  const int b = blockIdx.x, t = threadIdx.x;
  const int base = b * SCAN_TILE + t * 8;
  int vals[8];
  int s = 0;
  #pragma unroll
  for (int i = 0; i < 8; i++) {
    int idx = base + i;
    vals[i] = (idx < n) ? counts[idx] : 0;
    s += vals[i];
  }
  __shared__ int sums[256];
  sums[t] = s;
  __syncthreads();
  for (int o = 1; o < 256; o <<= 1) {
    int v = sums[t];
    int u = (t >= o) ? sums[t - o] : 0;
    __syncthreads();
    sums[t] = v + u;
    __syncthreads();
  }
  int run = partials[b] + ((t == 0) ? 0 : sums[t - 1]);
  #pragma unroll
  for (int i = 0; i < 8; i++) {
    int idx = base + i;
    if (idx < n) {
      offsets[idx] = run;
      cursor[idx] = run;
      run += vals[i];
    }
  }
  if (b == 0 && t == 0) offsets[n] = E;
}

__global__ __launch_bounds__(256) void scatter_ids_kernel(
    const int* __restrict__ edge, int* __restrict__ cursor, int* __restrict__ edge_list, int E)
{
  int e = blockIdx.x * 256 + threadIdx.x;
  if (e < E) {
    int d = edge[(size_t)e * 2];
    int p = atomicAdd(&cursor[d], 1);
    edge_list[p] = e;
  }
}

// ---------------- edge kernel: filter MLP (layer2 MFMA) + bf16 gather + gate +
// bf16 msg store at dst-sorted position (no atomics) ----------------
__global__ __launch_bounds__(256) void edge_mfma_msg_kernel(
    const unsigned short* __restrict__ so,  // [N,384] bf16
    const unsigned short* __restrict__ nv,  // [N,3,128] bf16
    const int*   __restrict__ edge,    // [E,2] (dst, src)
    const float* __restrict__ diff,    // [E,3]
    const float* __restrict__ dist,    // [E]
    const float* __restrict__ rbf,     // [E,20]
    const int*   __restrict__ edge_list,
    const float* __restrict__ w1, const float* __restrict__ b1, const float* __restrict__ a1p,
    const unsigned short* __restrict__ w2t, // [384][128] bf16
    const float* __restrict__ b2, const float* __restrict__ a2p,
    unsigned short* __restrict__ msg,  // [chunk][512] bf16
    int p0, int p1)
{
  __shared__ float R_lds[64][20];
  __shared__ __attribute__((aligned(16))) unsigned short h_lds[64 * HD];
  __shared__ __attribute__((aligned(16))) unsigned short P_lds[3][64 * HD];
  __shared__ int eid_l[64], src_l[64];
  __shared__ float unit_l[64][3];

  const int t = threadIdx.x;
  const int tx = t & 31, ty = t >> 5;
  const int c4 = tx * 4;
  const int wvid = t >> 6, lane = t & 63, l15 = lane & 15, l4 = lane >> 4;
  const int pblk = p0 + blockIdx.x * 64;
  const float a1 = a1p[0], a2 = a2p[0];

  if (t < 64) {
    int p = pblk + t;
    if (p < p1) {
      int e = edge_list[p];
      eid_l[t] = e;
      src_l[t] = edge[(size_t)e * 2 + 1];
      float inv = 1.f / dist[e];
      unit_l[t][0] = diff[(size_t)e * 3 + 0] * inv;
      unit_l[t][1] = diff[(size_t)e * 3 + 1] * inv;
      unit_l[t][2] = diff[(size_t)e * 3 + 2] * inv;
    } else {
      eid_l[t] = -1; src_l[t] = 0;
      unit_l[t][0] = 0.f; unit_l[t][1] = 0.f; unit_l[t][2] = 0.f;
    }
  }
  __syncthreads();   // S1

  for (int idx = t; idx < 64 * 20; idx += 256) {
    int r = idx / 20, k = idx - r * 20;
    int e = eid_l[r];
    R_lds[r][k] = (e >= 0) ? rbf[(size_t)e * 20 + k] : 0.f;
  }
  __syncthreads();   // S2

  // layer1 (K=20, fp32) -> h bf16 swizzled
  {
    float ha[8][4];
    f32x4 bv = *(const f32x4*)&b1[c4];
    #pragma unroll
    for (int rr = 0; rr < 8; rr++)
      #pragma unroll
      for (int cc = 0; cc < 4; cc++) ha[rr][cc] = bv[cc];
    for (int k = 0; k < 20; k++) {
      f32x4 wvv = *(const f32x4*)&w1[(size_t)k * HD + c4];
      #pragma unroll
      for (int rr = 0; rr < 8; rr++) {
        float av = R_lds[ty * 8 + rr][k];
        #pragma unroll
        for (int cc = 0; cc < 4; cc++) ha[rr][cc] += av * wvv[cc];
      }
    }
    #pragma unroll
    for (int rr = 0; rr < 8; rr++) {
      int row = ty * 8 + rr;
      ushort4 hp;
      hp.x = f2bf(prelu_f(ha[rr][0], a1));
      hp.y = f2bf(prelu_f(ha[rr][1], a1));
      hp.z = f2bf(prelu_f(ha[rr][2], a1));
      hp.w = f2bf(prelu_f(ha[rr][3], a1));
      *(ushort4*)&h_lds[row * HD + (c4 ^ ((row & 7) << 3))] = hp;
    }
  }
  __syncthreads();   // S3

  // layer2 MFMA: 3 planes -> P_lds
  for (int m = 0; m < 3; m++) {
    bf16x8 Bf[2][4];
    #pragma unroll
    for (int nf = 0; nf < 2; nf++)
      #pragma unroll
      for (int ks = 0; ks < 4; ks++) {
        int col = m * 128 + wvid * 32 + nf * 16 + l15;
        Bf[nf][ks] = *(const bf16x8*)&w2t[(size_t)col * 128 + ks * 32 + l4 * 8];
      }
    f32x4 D[4][2];
    #pragma unroll
    for (int mi = 0; mi < 4; mi++)
      #pragma unroll
      for (int nf = 0; nf < 2; nf++)
        #pragma unroll
        for (int cc = 0; cc < 4; cc++) D[mi][nf][cc] = 0.f;

    #pragma unroll
    for (int mi = 0; mi < 4; mi++)
      #pragma unroll
      for (int ks = 0; ks < 4; ks++) {
        int row = mi * 16 + l15;
        bf16x8 Af = *(const bf16x8*)&h_lds[row * HD + ((ks * 32 + l4 * 8) ^ ((row & 7) << 3))];
        D[mi][0] = __builtin_amdgcn_mfma_f32_16x16x32_bf16(Af, Bf[0][ks], D[mi][0], 0, 0, 0);
        D[mi][1] = __builtin_amdgcn_mfma_f32_16x16x32_bf16(Af, Bf[1][ks], D[mi][1], 0, 0, 0);
      }

    float b2v0 = b2[m * 128 + wvid * 32 + l15];
    float b2v1 = b2[m * 128 + wvid * 32 + 16 + l15];
    #pragma unroll
    for (int mi = 0; mi < 4; mi++)
      #pragma unroll
      for (int nf = 0; nf < 2; nf++)
        #pragma unroll
        for (int r4 = 0; r4 < 4; r4++) {
          int row = mi * 16 + l4 * 4 + r4;
          int col = wvid * 32 + nf * 16 + l15;
          float v = prelu_f(D[mi][nf][r4] + (nf ? b2v1 : b2v0), a2);
          P_lds[m][row * HD + (col ^ ((row & 7) << 3))] = f2bf(v);
        }
  }
  __syncthreads();   // S4

  // epilogue: bf16 gather + gate + bf16 msg store
  #pragma unroll
  for (int rr = 0; rr < 8; rr++) {
    const int r = ty * 8 + rr;
    const int p = pblk + r;
    if (p >= p1) continue;
    const int src = src_l[r];
    const int sc = c4 ^ ((r & 7) << 3);
    f32x4 gvp = bf4_to_f32(*(const ushort4*)&P_lds[0][r * HD + sc]);
    f32x4 msp = bf4_to_f32(*(const ushort4*)&P_lds[1][r * HD + sc]);
    f32x4 gep = bf4_to_f32(*(const ushort4*)&P_lds[2][r * HD + sc]);
    const size_t sb = (size_t)src * 384;
    f32x4 s0 = bf4_to_f32(*(const ushort4*)&so[sb + c4]);
    f32x4 s1 = bf4_to_f32(*(const ushort4*)&so[sb + HD + c4]);
    f32x4 s2 = bf4_to_f32(*(const ushort4*)&so[sb + 2 * HD + c4]);
    f32x4 v0 = bf4_to_f32(*(const ushort4*)&nv[sb + c4]);
    f32x4 v1 = bf4_to_f32(*(const ushort4*)&nv[sb + HD + c4]);
    f32x4 v2 = bf4_to_f32(*(const ushort4*)&nv[sb + 2 * HD + c4]);
    const float u0 = unit_l[r][0], u1 = unit_l[r][1], u2 = unit_l[r][2];
    f32x4 gv, ms, ge;
    #pragma unroll
    for (int cc = 0; cc < 4; cc++) {
      gv[cc] = gvp[cc] * s0[cc];
      ms[cc] = msp[cc] * s1[cc];
      ge[cc] = gep[cc] * s2[cc];
    }
    unsigned short* mrow = msg + (size_t)(p - p0) * 512;
    ushort4 pk;
    pk.x = f2bf(ms[0]); pk.y = f2bf(ms[1]); pk.z = f2bf(ms[2]); pk.w = f2bf(ms[3]);
    *(ushort4*)&mrow[c4] = pk;
    #pragma unroll
    for (int d = 0; d < 3; d++) {
      f32x4 vd = (d == 0) ? v0 : (d == 1) ? v1 : v2;
      const float ud = (d == 0) ? u0 : (d == 1) ? u1 : u2;
      f32x4 mv;
      #pragma unroll
      for (int cc = 0; cc < 4; cc++) mv[cc] = vd[cc] * gv[cc] + ud * ge[cc];
      ushort4 pv;
      pv.x = f2bf(mv[0]); pv.y = f2bf(mv[1]); pv.z = f2bf(mv[2]); pv.w = f2bf(mv[3]);
      *(ushort4*)&mrow[(1 + d) * HD + c4] = pv;
    }
  }
}

// ---------------- per-node segment sum of messages ----------------
// mode 0: out = residual(ns/nv) + acc   (first pass, writes every element)
// mode 1: out += acc                    (subsequent chunks/branch)
__global__ __launch_bounds__(256) void gather_kernel(
    const unsigned short* __restrict__ msg,
    const int* __restrict__ offsets,
    const float* __restrict__ ns, const float* __restrict__ nvec,
    float* __restrict__ out, int N, int p0, int p1, int mode)
{
  const int node = blockIdx.x * 2 + (threadIdx.x >> 7);
  if (node >= N) return;
  const int t = threadIdx.x & 127;
  int s = offsets[node], e = offsets[node + 1];
  s = max(s, p0); e = min(e, p1);
  if (mode && s >= e) return;
  const int j = t * 4;
  f32x4 acc = {0.f, 0.f, 0.f, 0.f};
  for (int p = s; p < e; p++) {
    ushort4 u = *(const ushort4*)&msg[(size_t)(p - p0) * 512 + j];
    acc[0] += bf2f(u.x); acc[1] += bf2f(u.y);
    acc[2] += bf2f(u.z); acc[3] += bf2f(u.w);
  }
  size_t o = (j < 128) ? ((size_t)node * HD + j)
                       : ((size_t)N * HD + ((size_t)node * 3 + (j >> 7) - 1) * HD + (j & 127));
  f32x4 base;
  if (mode) {
    base = *(f32x4*)&out[o];
  } else {
    base = (j < 128) ? *(const f32x4*)&ns[(size_t)node * HD + j]
                     : *(const f32x4*)&nvec[(size_t)node * 384 + (j - 128)];
  }
  base += acc;
  *(f32x4*)&out[o] = base;
}

extern "C" void kernel_launch(void* const* d_in, const int* in_sizes, int n_in,
                              void* d_out, int out_size, void* d_ws, size_t ws_size,
                              hipStream_t stream)
{
  const float* node_scalar = (const float*)d_in[0];
  const float* node_vector = (const float*)d_in[1];
  const int*   che_edge = (const int*)d_in[2];
  const float* che_diff = (const float*)d_in[3];
  const float* che_dist = (const float*)d_in[4];
  const float* che_rbf  = (const float*)d_in[5];
  const int*   vdw_edge = (const int*)d_in[6];
  const float* vdw_diff = (const float*)d_in[7];
  const float* vdw_dist = (const float*)d_in[8];
  const float* vdw_rbf  = (const float*)d_in[9];
  const float* mlp_p[24];
  for (int i = 0; i < 24; i++) mlp_p[i] = (const float*)d_in[10 + i];
  // [che_s 0..5][che_f 6..11][vdw_s 12..17][vdw_f 18..23]

  const int N = in_sizes[0] / HD;
  const int E_che = in_sizes[4];
  const int E_vdw = in_sizes[8];
  const int E_max = E_che > E_vdw ? E_che : E_vdw;
  const int nb_scan = (N + SCAN_TILE - 1) / SCAN_TILE;

  // workspace layout
  char* wp = (char*)d_ws;
  size_t off = 0;
  unsigned short* so_bf = (unsigned short*)(wp + off); off += (size_t)N * 384 * 2;
  unsigned short* nv_bf = (unsigned short*)(wp + off); off += (size_t)N * 384 * 2;
  int* counts     = (int*)(wp + off);   off += (size_t)N * 4;
  int* cursor     = (int*)(wp + off);   off += (size_t)N * 4;
  int* offsets    = (int*)(wp + off);   off += (size_t)(N + 1) * 4;
  int* partials   = (int*)(wp + off);   off += 256 * 4;
  off = (off + 255) & ~(size_t)255;
  int* edge_list  = (int*)(wp + off);   off += (size_t)E_max * 4;
  off = (off + 255) & ~(size_t)255;
  unsigned short* w2t_sche = (unsigned short*)(wp + off); off += 384 * 128 * 2;
  unsigned short* w2t_fche = (unsigned short*)(wp + off); off += 384 * 128 * 2;
  unsigned short* w2t_svdw = (unsigned short*)(wp + off); off += 384 * 128 * 2;
  unsigned short* w2t_fvdw = (unsigned short*)(wp + off); off += 384 * 128 * 2;
  off = (off + 255) & ~(size_t)255;
  unsigned short* msg = (unsigned short*)(wp + off);
  size_t cap_edges = (ws_size > off) ? (ws_size - off) / 1024 : 0;  // 512 bf16 per edge
  cap_edges &= ~(size_t)63;
  if (cap_edges > CHUNK_EDGES) cap_edges = CHUNK_EDGES;

  const int n_nv4 = N * 3 * HD / 4;
  conv_bf16_kernel<<<(n_nv4 + 255) / 256, 256, 0, stream>>>(
      (const f32x4*)node_vector, (ushort4*)nv_bf, n_nv4);

  tconv_kernel<<<192, 256, 0, stream>>>(mlp_p[3],  w2t_sche);
  tconv_kernel<<<192, 256, 0, stream>>>(mlp_p[9],  w2t_fche);
  tconv_kernel<<<192, 256, 0, stream>>>(mlp_p[15], w2t_svdw);
  tconv_kernel<<<192, 256, 0, stream>>>(mlp_p[21], w2t_fvdw);

  for (int br = 0; br < 2; br++) {
    const int*   edge = br == 0 ? che_edge : vdw_edge;
    const float* diff = br == 0 ? che_diff : vdw_diff;
    const float* dist = br == 0 ? che_dist : vdw_dist;
    const float* rbf  = br == 0 ? che_rbf  : vdw_rbf;
    const int    E    = br == 0 ? E_che : E_vdw;
    const float* const* sp = &mlp_p[br == 0 ? 0 : 12];
    const float* const* fp = &mlp_p[br == 0 ? 6 : 18];
    const unsigned short* w2t_s = br == 0 ? w2t_sche : w2t_svdw;
    const unsigned short* w2t_f = br == 0 ? w2t_fche : w2t_fvdw;

    node_mlp_hybrid<<<(N + 63) / 64, 256, 0, stream>>>(
        node_scalar, sp[0], sp[1], sp[2], w2t_s, sp[4], sp[5], so_bf, N);

    zero_int_kernel<<<(N + 255) / 256, 256, 0, stream>>>(counts, N);
    hist_kernel<<<(E + 255) / 256, 256, 0, stream>>>(edge, counts, E);
    scan_partial_kernel<<<nb_scan, 256, 0, stream>>>(counts, partials, N);
    scan_partials_kernel<<<1, 256, 0, stream>>>(partials, nb_scan);
    scan_write_kernel<<<nb_scan, 256, 0, stream>>>(counts, partials, offsets, cursor, N, E);
    scatter_ids_kernel<<<(E + 255) / 256, 256, 0, stream>>>(edge, cursor, edge_list, E);

    int cap = (int)(cap_edges > (size_t)E ? (size_t)E : cap_edges);
    if (cap < 64) cap = 64;
    for (int p0 = 0; p0 < E; p0 += cap) {
      int p1 = p0 + cap < E ? p0 + cap : E;
      int nblk = (p1 - p0 + 63) / 64;
      edge_mfma_msg_kernel<<<nblk, 256, 0, stream>>>(
          so_bf, nv_bf, edge, diff, dist, rbf, edge_list,
          fp[0], fp[1], fp[2], w2t_f, fp[4], fp[5], msg, p0, p1);
      int mode = (br == 0 && p0 == 0) ? 0 : 1;
      gather_kernel<<<(N + 1) / 2, 256, 0, stream>>>(
          msg, offsets, node_scalar, node_vector, (float*)d_out, N, p0, p1, mode);
    }
  }
}

// Round 8
// 824.662 us; speedup vs baseline: 2.3847x; 1.2157x over previous
//
#include <hip/hip_runtime.h>

typedef float f32x4 __attribute__((ext_vector_type(4)));
typedef short bf16x8 __attribute__((ext_vector_type(8)));

#define HD 128
#define SCAN_TILE 2048      // counts per scan block (256 thr x 8)

__device__ __forceinline__ float prelu_f(float x, float a) {
  return x > 0.f ? x : a * x;
}

__device__ __forceinline__ unsigned short f2bf(float x) {
  union { float f; unsigned u; } a; a.f = x;
  unsigned r = a.u + 0x7fffu + ((a.u >> 16) & 1u);
  return (unsigned short)(r >> 16);
}
__device__ __forceinline__ float bf2f(unsigned short u) {
  union { unsigned u; float f; } a; a.u = ((unsigned)u) << 16;
  return a.f;
}
__device__ __forceinline__ f32x4 bf4_to_f32(ushort4 u) {
  f32x4 r; r[0] = bf2f(u.x); r[1] = bf2f(u.y); r[2] = bf2f(u.z); r[3] = bf2f(u.w);
  return r;
}

// out = concat(node_scalar, node_vector)  (residual init)
__global__ __launch_bounds__(256) void init_out_kernel(
    const f32x4* __restrict__ ns, const f32x4* __restrict__ nv,
    f32x4* __restrict__ out, int n_ns4, int n_nv4)
{
  int total = n_ns4 + n_nv4;
  for (int i = blockIdx.x * 256 + threadIdx.x; i < total; i += gridDim.x * 256)
    out[i] = (i < n_ns4) ? ns[i] : nv[i - n_ns4];
}

// transpose+convert: src[128][384] f32 -> dst[384][128] bf16
__global__ __launch_bounds__(256) void tconv_kernel(
    const float* __restrict__ src, unsigned short* __restrict__ dst)
{
  int idx = blockIdx.x * 256 + threadIdx.x;
  if (idx < 384 * 128) {
    int c = idx >> 7, k = idx & 127;
    dst[idx] = f2bf(src[(size_t)k * 384 + c]);
  }
}

// f32 -> bf16 bulk convert (vectorized)
__global__ __launch_bounds__(256) void conv_bf16_kernel(
    const f32x4* __restrict__ src, ushort4* __restrict__ dst, int n4)
{
  int i = blockIdx.x * 256 + threadIdx.x;
  if (i < n4) {
    f32x4 v = src[i];
    ushort4 o;
    o.x = f2bf(v[0]); o.y = f2bf(v[1]); o.z = f2bf(v[2]); o.w = f2bf(v[3]);
    dst[i] = o;
  }
}

// ---------------- node MLP: layer1 fp32 VALU, layer2 bf16 MFMA, bf16 output ----------------
__global__ __launch_bounds__(256) void node_mlp_hybrid(
    const float* __restrict__ A,
    const float* __restrict__ w1, const float* __restrict__ b1, const float* __restrict__ a1p,
    const unsigned short* __restrict__ w2t,  // [384][128] bf16
    const float* __restrict__ b2, const float* __restrict__ a2p,
    unsigned short* __restrict__ out,        // [M,384] bf16
    int M)
{
  __shared__ float A_lds[64][HD];
  __shared__ __attribute__((aligned(16))) unsigned short h_lds[64 * HD];
  const int t = threadIdx.x;
  const int tx = t & 31, ty = t >> 5;
  const int c4 = tx * 4;
  const int wvid = t >> 6, lane = t & 63, l15 = lane & 15, l4 = lane >> 4;
  const int m0 = blockIdx.x * 64;
  const float a1 = a1p[0], a2 = a2p[0];

  for (int idx = t; idx < 64 * HD / 4; idx += 256) {
    int r = idx >> 5, cc = (idx & 31) * 4;
    f32x4 v = {0.f, 0.f, 0.f, 0.f};
    if (m0 + r < M) v = *(const f32x4*)&A[(size_t)(m0 + r) * HD + cc];
    *(f32x4*)&A_lds[r][cc] = v;
  }
  __syncthreads();

  // layer1 fp32 -> h bf16 (swizzled)
  {
    float acc[8][4];
    f32x4 bv = *(const f32x4*)&b1[c4];
    #pragma unroll
    for (int rr = 0; rr < 8; rr++)
      #pragma unroll
      for (int cc = 0; cc < 4; cc++) acc[rr][cc] = bv[cc];

    for (int kg = 0; kg < HD / 4; kg++) {
      const int k = kg * 4;
      f32x4 wv[4];
      #pragma unroll
      for (int kk = 0; kk < 4; kk++) wv[kk] = *(const f32x4*)&w1[(size_t)(k + kk) * HD + c4];
      #pragma unroll
      for (int rr = 0; rr < 8; rr++) {
        f32x4 av = *(const f32x4*)&A_lds[ty * 8 + rr][k];
        #pragma unroll
        for (int cc = 0; cc < 4; cc++)
          #pragma unroll
          for (int kk = 0; kk < 4; kk++)
            acc[rr][cc] += av[kk] * wv[kk][cc];
      }
    }
    #pragma unroll
    for (int rr = 0; rr < 8; rr++) {
      int row = ty * 8 + rr;
      ushort4 hp;
      hp.x = f2bf(prelu_f(acc[rr][0], a1));
      hp.y = f2bf(prelu_f(acc[rr][1], a1));
      hp.z = f2bf(prelu_f(acc[rr][2], a1));
      hp.w = f2bf(prelu_f(acc[rr][3], a1));
      *(ushort4*)&h_lds[row * HD + (c4 ^ ((row & 7) << 3))] = hp;
    }
  }
  __syncthreads();

  // layer2 MFMA: 3 plane groups of 128 cols
  for (int m = 0; m < 3; m++) {
    bf16x8 Bf[2][4];
    #pragma unroll
    for (int nf = 0; nf < 2; nf++)
      #pragma unroll
      for (int ks = 0; ks < 4; ks++) {
        int col = m * 128 + wvid * 32 + nf * 16 + l15;
        Bf[nf][ks] = *(const bf16x8*)&w2t[(size_t)col * 128 + ks * 32 + l4 * 8];
      }
    f32x4 D[4][2];
    #pragma unroll
    for (int mi = 0; mi < 4; mi++)
      #pragma unroll
      for (int nf = 0; nf < 2; nf++)
        #pragma unroll
        for (int cc = 0; cc < 4; cc++) D[mi][nf][cc] = 0.f;

    #pragma unroll
    for (int mi = 0; mi < 4; mi++)
      #pragma unroll
      for (int ks = 0; ks < 4; ks++) {
        int row = mi * 16 + l15;
        bf16x8 Af = *(const bf16x8*)&h_lds[row * HD + ((ks * 32 + l4 * 8) ^ ((row & 7) << 3))];
        D[mi][0] = __builtin_amdgcn_mfma_f32_16x16x32_bf16(Af, Bf[0][ks], D[mi][0], 0, 0, 0);
        D[mi][1] = __builtin_amdgcn_mfma_f32_16x16x32_bf16(Af, Bf[1][ks], D[mi][1], 0, 0, 0);
      }

    float b2v0 = b2[m * 128 + wvid * 32 + l15];
    float b2v1 = b2[m * 128 + wvid * 32 + 16 + l15];
    #pragma unroll
    for (int mi = 0; mi < 4; mi++)
      #pragma unroll
      for (int nf = 0; nf < 2; nf++)
        #pragma unroll
        for (int r4 = 0; r4 < 4; r4++) {
          int row = mi * 16 + l4 * 4 + r4;
          if (m0 + row < M) {
            int col = m * 128 + wvid * 32 + nf * 16 + l15;
            out[(size_t)(m0 + row) * 384 + col] =
                f2bf(prelu_f(D[mi][nf][r4] + (nf ? b2v1 : b2v0), a2));
          }
        }
  }
}

// ---------------- CSR build ----------------
__global__ __launch_bounds__(256) void zero_int_kernel(int* __restrict__ p, int n) {
  int i = blockIdx.x * 256 + threadIdx.x;
  if (i < n) p[i] = 0;
}

__global__ __launch_bounds__(256) void hist_kernel(const int* __restrict__ edge, int* __restrict__ counts, int E) {
  int e = blockIdx.x * 256 + threadIdx.x;
  if (e < E) atomicAdd(&counts[edge[(size_t)e * 2]], 1);
}

__global__ __launch_bounds__(256) void scan_partial_kernel(
    const int* __restrict__ counts, int* __restrict__ partials, int n)
{
  const int b = blockIdx.x, t = threadIdx.x;
  const int base = b * SCAN_TILE + t * 8;
  int s = 0;
  #pragma unroll
  for (int i = 0; i < 8; i++) {
    int idx = base + i;
    if (idx < n) s += counts[idx];
  }
  __shared__ int sums[256];
  sums[t] = s;
  __syncthreads();
  for (int o = 128; o > 0; o >>= 1) {
    if (t < o) sums[t] += sums[t + o];
    __syncthreads();
  }
  if (t == 0) partials[b] = sums[0];
}

__global__ __launch_bounds__(256) void scan_partials_kernel(int* __restrict__ partials, int nb)
{
  __shared__ int s[256];
  const int t = threadIdx.x;
  s[t] = (t < nb) ? partials[t] : 0;
  __syncthreads();
  for (int o = 1; o < 256; o <<= 1) {
    int v = s[t];
    int u = (t >= o) ? s[t - o] : 0;
    __syncthreads();
    s[t] = v + u;
    __syncthreads();
  }
  if (t < nb) partials[t] = (t == 0) ? 0 : s[t - 1];
}

__global__ __launch_bounds__(256) void scan_write_kernel(
    const int* __restrict__ counts, const int* __restrict__ partials,
    int* __restrict__ offsets, int* __restrict__ cursor, int n, int E)
{
  const int b = blockIdx.x, t = threadIdx.x;
  const int base = b * SCAN_TILE + t * 8;
  int vals[8];
  int s = 0;
  #pragma unroll
  for (int i = 0; i < 8; i++) {
    int idx = base + i;
    vals[i] = (idx < n) ? counts[idx] : 0;
    s += vals[i];
  }
  __shared__ int sums[256];
  sums[t] = s;
  __syncthreads();
  for (int o = 1; o < 256; o <<= 1) {
    int v = sums[t];
    int u = (t >= o) ? sums[t - o] : 0;
    __syncthreads();
    sums[t] = v + u;
    __syncthreads();
  }
  int run = partials[b] + ((t == 0) ? 0 : sums[t - 1]);
  #pragma unroll
  for (int i = 0; i < 8; i++) {
    int idx = base + i;
    if (idx < n) {
      offsets[idx] = run;
      cursor[idx] = run;
      run += vals[i];
    }
  }
  if (b == 0 && t == 0) offsets[n] = E;
}

__global__ __launch_bounds__(256) void scatter_ids_kernel(
    const int* __restrict__ edge, int* __restrict__ cursor, int* __restrict__ edge_list, int E)
{
  int e = blockIdx.x * 256 + threadIdx.x;
  if (e < E) {
    int d = edge[(size_t)e * 2];
    int p = atomicAdd(&cursor[d], 1);
    edge_list[p] = e;
  }
}

// ---------------- fused edge kernel: filter MLP (layer2 MFMA) + bf16 gather +
// gate + in-LDS segmented reduction + direct RMW / boundary atomics ----------------
__global__ __launch_bounds__(256) void edge_mfma_reduce_kernel(
    const unsigned short* __restrict__ so,  // [N,384] bf16
    const unsigned short* __restrict__ nv,  // [N,3,128] bf16
    const int*   __restrict__ edge,    // [E,2] (dst, src)
    const float* __restrict__ diff,    // [E,3]
    const float* __restrict__ dist,    // [E]
    const float* __restrict__ rbf,     // [E,20]
    const int*   __restrict__ edge_list,
    const int*   __restrict__ offsets, // [N+1]
    const float* __restrict__ w1, const float* __restrict__ b1, const float* __restrict__ a1p,
    const unsigned short* __restrict__ w2t, // [384][128] bf16
    const float* __restrict__ b2, const float* __restrict__ a2p,
    float* __restrict__ out,           // [N,128]+[N,3,128] residual-initialized
    int N, int E)
{
  __shared__ float R_lds[64][20];
  __shared__ __attribute__((aligned(16))) unsigned short h_lds[64 * HD];
  __shared__ __attribute__((aligned(16))) unsigned short P_lds[3][64 * HD];
  __shared__ int eid_l[64], src_l[64], dst_l[64];
  __shared__ float unit_l[64][3];
  __shared__ int run_rs[65], run_node[64], run_flag[64];
  __shared__ int nd_s;

  const int t = threadIdx.x;
  const int tx = t & 31, ty = t >> 5;
  const int c4 = tx * 4;
  const int wvid = t >> 6, lane = t & 63, l15 = lane & 15, l4 = lane >> 4;
  const int pblk = blockIdx.x * 64;
  const int nrows = min(64, E - pblk);
  const float a1 = a1p[0], a2 = a2p[0];

  if (t < 64) {
    int p = pblk + t;
    if (t < nrows) {
      int e = edge_list[p];
      eid_l[t] = e;
      src_l[t] = edge[(size_t)e * 2 + 1];
      dst_l[t] = edge[(size_t)e * 2 + 0];
      float inv = 1.f / dist[e];
      unit_l[t][0] = diff[(size_t)e * 3 + 0] * inv;
      unit_l[t][1] = diff[(size_t)e * 3 + 1] * inv;
      unit_l[t][2] = diff[(size_t)e * 3 + 2] * inv;
    } else {
      eid_l[t] = -1; src_l[t] = 0; dst_l[t] = -1;
      unit_l[t][0] = 0.f; unit_l[t][1] = 0.f; unit_l[t][2] = 0.f;
    }
  }
  __syncthreads();   // S1

  // wave 0: dst-run detection + interior/boundary classification
  if (t < 64) {
    bool flag = (t < nrows) && (t == 0 || dst_l[t] != dst_l[t - 1]);
    unsigned long long mask = __ballot(flag ? 1 : 0);
    if (flag) {
      int j = __popcll(mask & ((1ull << t) - 1ull));
      int n = dst_l[t];
      run_rs[j] = t;
      run_node[j] = n;
      unsigned long long rest = (t == 63) ? 0ull : (mask >> (t + 1));
      int re = rest ? (t + 1 + (__ffsll((long long)rest) - 1)) : nrows;
      int interior = 1;
      if (t == 0 && offsets[n] != pblk) interior = 0;
      if (re == nrows && offsets[n + 1] != pblk + nrows) interior = 0;
      run_flag[j] = interior;
    }
    if (t == 0) {
      int nd = __popcll(mask);
      nd_s = nd;
      run_rs[nd] = nrows;
    }
  }

  for (int idx = t; idx < 64 * 20; idx += 256) {
    int r = idx / 20, k = idx - r * 20;
    int e = eid_l[r];
    R_lds[r][k] = (e >= 0) ? rbf[(size_t)e * 20 + k] : 0.f;
  }
  __syncthreads();   // S2

  // layer1 (K=20, fp32) -> h bf16 swizzled
  {
    float ha[8][4];
    f32x4 bv = *(const f32x4*)&b1[c4];
    #pragma unroll
    for (int rr = 0; rr < 8; rr++)
      #pragma unroll
      for (int cc = 0; cc < 4; cc++) ha[rr][cc] = bv[cc];
    for (int k = 0; k < 20; k++) {
      f32x4 wvv = *(const f32x4*)&w1[(size_t)k * HD + c4];
      #pragma unroll
      for (int rr = 0; rr < 8; rr++) {
        float av = R_lds[ty * 8 + rr][k];
        #pragma unroll
        for (int cc = 0; cc < 4; cc++) ha[rr][cc] += av * wvv[cc];
      }
    }
    #pragma unroll
    for (int rr = 0; rr < 8; rr++) {
      int row = ty * 8 + rr;
      ushort4 hp;
      hp.x = f2bf(prelu_f(ha[rr][0], a1));
      hp.y = f2bf(prelu_f(ha[rr][1], a1));
      hp.z = f2bf(prelu_f(ha[rr][2], a1));
      hp.w = f2bf(prelu_f(ha[rr][3], a1));
      *(ushort4*)&h_lds[row * HD + (c4 ^ ((row & 7) << 3))] = hp;
    }
  }
  __syncthreads();   // S3

  // layer2 MFMA: 3 planes -> P_lds (gv, ms, ge gates)
  for (int m = 0; m < 3; m++) {
    bf16x8 Bf[2][4];
    #pragma unroll
    for (int nf = 0; nf < 2; nf++)
      #pragma unroll
      for (int ks = 0; ks < 4; ks++) {
        int col = m * 128 + wvid * 32 + nf * 16 + l15;
        Bf[nf][ks] = *(const bf16x8*)&w2t[(size_t)col * 128 + ks * 32 + l4 * 8];
      }
    f32x4 D[4][2];
    #pragma unroll
    for (int mi = 0; mi < 4; mi++)
      #pragma unroll
      for (int nf = 0; nf < 2; nf++)
        #pragma unroll
        for (int cc = 0; cc < 4; cc++) D[mi][nf][cc] = 0.f;

    #pragma unroll
    for (int mi = 0; mi < 4; mi++)
      #pragma unroll
      for (int ks = 0; ks < 4; ks++) {
        int row = mi * 16 + l15;
        bf16x8 Af = *(const bf16x8*)&h_lds[row * HD + ((ks * 32 + l4 * 8) ^ ((row & 7) << 3))];
        D[mi][0] = __builtin_amdgcn_mfma_f32_16x16x32_bf16(Af, Bf[0][ks], D[mi][0], 0, 0, 0);
        D[mi][1] = __builtin_amdgcn_mfma_f32_16x16x32_bf16(Af, Bf[1][ks], D[mi][1], 0, 0, 0);
      }

    float b2v0 = b2[m * 128 + wvid * 32 + l15];
    float b2v1 = b2[m * 128 + wvid * 32 + 16 + l15];
    #pragma unroll
    for (int mi = 0; mi < 4; mi++)
      #pragma unroll
      for (int nf = 0; nf < 2; nf++)
        #pragma unroll
        for (int r4 = 0; r4 < 4; r4++) {
          int row = mi * 16 + l4 * 4 + r4;
          int col = wvid * 32 + nf * 16 + l15;
          float v = prelu_f(D[mi][nf][r4] + (nf ? b2v1 : b2v0), a2);
          P_lds[m][row * HD + (col ^ ((row & 7) << 3))] = f2bf(v);
        }
  }
  __syncthreads();   // S4

  // epilogue A (owner phase): gather + gate; overwrite LDS planes in place with
  // final messages: ms -> h_lds, mv0/1/2 -> P_lds[0/1/2]. Per-cell exclusive.
  #pragma unroll
  for (int rr = 0; rr < 8; rr++) {
    const int r = ty * 8 + rr;
    const int src = src_l[r];
    const int sc = c4 ^ ((r & 7) << 3);
    f32x4 gvp = bf4_to_f32(*(const ushort4*)&P_lds[0][r * HD + sc]);
    f32x4 msp = bf4_to_f32(*(const ushort4*)&P_lds[1][r * HD + sc]);
    f32x4 gep = bf4_to_f32(*(const ushort4*)&P_lds[2][r * HD + sc]);
    const size_t sb = (size_t)src * 384;
    f32x4 s0 = bf4_to_f32(*(const ushort4*)&so[sb + c4]);
    f32x4 s1 = bf4_to_f32(*(const ushort4*)&so[sb + HD + c4]);
    f32x4 s2 = bf4_to_f32(*(const ushort4*)&so[sb + 2 * HD + c4]);
    f32x4 v0 = bf4_to_f32(*(const ushort4*)&nv[sb + c4]);
    f32x4 v1 = bf4_to_f32(*(const ushort4*)&nv[sb + HD + c4]);
    f32x4 v2 = bf4_to_f32(*(const ushort4*)&nv[sb + 2 * HD + c4]);
    const float u0 = unit_l[r][0], u1 = unit_l[r][1], u2 = unit_l[r][2];
    ushort4 msw, m0w, m1w, m2w;
    #pragma unroll
    for (int cc = 0; cc < 4; cc++) {
      float gv = gvp[cc] * s0[cc];
      float ms = msp[cc] * s1[cc];
      float ge = gep[cc] * s2[cc];
      float mv0 = v0[cc] * gv + u0 * ge;
      float mv1 = v1[cc] * gv + u1 * ge;
      float mv2 = v2[cc] * gv + u2 * ge;
      ((unsigned short*)&msw)[cc] = f2bf(ms);
      ((unsigned short*)&m0w)[cc] = f2bf(mv0);
      ((unsigned short*)&m1w)[cc] = f2bf(mv1);
      ((unsigned short*)&m2w)[cc] = f2bf(mv2);
    }
    *(ushort4*)&h_lds[r * HD + sc]    = msw;
    *(ushort4*)&P_lds[0][r * HD + sc] = m0w;
    *(ushort4*)&P_lds[1][r * HD + sc] = m1w;
    *(ushort4*)&P_lds[2][r * HD + sc] = m2w;
  }
  __syncthreads();   // S5

  // epilogue B (reduction phase): thread t owns 2 cols of one of 4 planes;
  // segment-sum over dst runs; interior -> plain f32x2 RMW, boundary -> atomics.
  {
    const int pl = t >> 6;            // 0: ms, 1..3: mv0..2
    const int c2 = (t & 63) * 2;
    const unsigned short* region = (pl == 0) ? h_lds : &P_lds[pl - 1][0];
    float* out_v = out + (size_t)N * HD;
    const int nd = nd_s;
    for (int j = 0; j < nd; j++) {
      const int rs = run_rs[j], re = run_rs[j + 1];
      const int n = run_node[j];
      float a0 = 0.f, a1v = 0.f;
      for (int r = rs; r < re; r++) {
        int ad = r * HD + (((c2 & ~3) ^ ((r & 7) << 3)) | (c2 & 3));
        unsigned int u = *(const unsigned int*)&region[ad];
        a0  += bf2f((unsigned short)(u & 0xffffu));
        a1v += bf2f((unsigned short)(u >> 16));
      }
      float* dstp = (pl == 0) ? (out + (size_t)n * HD + c2)
                              : (out_v + (size_t)n * 384 + (size_t)(pl - 1) * HD + c2);
      if (run_flag[j]) {
        float2 cur = *(float2*)dstp;
        cur.x += a0; cur.y += a1v;
        *(float2*)dstp = cur;
      } else {
        atomicAdd(dstp, a0);
        atomicAdd(dstp + 1, a1v);
      }
    }
  }
}

extern "C" void kernel_launch(void* const* d_in, const int* in_sizes, int n_in,
                              void* d_out, int out_size, void* d_ws, size_t ws_size,
                              hipStream_t stream)
{
  const float* node_scalar = (const float*)d_in[0];
  const float* node_vector = (const float*)d_in[1];
  const int*   che_edge = (const int*)d_in[2];
  const float* che_diff = (const float*)d_in[3];
  const float* che_dist = (const float*)d_in[4];
  const float* che_rbf  = (const float*)d_in[5];
  const int*   vdw_edge = (const int*)d_in[6];
  const float* vdw_diff = (const float*)d_in[7];
  const float* vdw_dist = (const float*)d_in[8];
  const float* vdw_rbf  = (const float*)d_in[9];
  const float* mlp_p[24];
  for (int i = 0; i < 24; i++) mlp_p[i] = (const float*)d_in[10 + i];
  // [che_s 0..5][che_f 6..11][vdw_s 12..17][vdw_f 18..23]

  const int N = in_sizes[0] / HD;
  const int E_che = in_sizes[4];
  const int E_vdw = in_sizes[8];
  const int E_max = E_che > E_vdw ? E_che : E_vdw;
  const int nb_scan = (N + SCAN_TILE - 1) / SCAN_TILE;

  // workspace layout
  char* wp = (char*)d_ws;
  size_t off = 0;
  unsigned short* so_bf = (unsigned short*)(wp + off); off += (size_t)N * 384 * 2;
  unsigned short* nv_bf = (unsigned short*)(wp + off); off += (size_t)N * 384 * 2;
  int* counts     = (int*)(wp + off);   off += (size_t)N * 4;
  int* cursor     = (int*)(wp + off);   off += (size_t)N * 4;
  int* offsets    = (int*)(wp + off);   off += (size_t)(N + 1) * 4;
  int* partials   = (int*)(wp + off);   off += 256 * 4;
  off = (off + 255) & ~(size_t)255;
  int* edge_list  = (int*)(wp + off);   off += (size_t)E_max * 4;
  off = (off + 255) & ~(size_t)255;
  unsigned short* w2t_sche = (unsigned short*)(wp + off); off += 384 * 128 * 2;
  unsigned short* w2t_fche = (unsigned short*)(wp + off); off += 384 * 128 * 2;
  unsigned short* w2t_svdw = (unsigned short*)(wp + off); off += 384 * 128 * 2;
  unsigned short* w2t_fvdw = (unsigned short*)(wp + off); off += 384 * 128 * 2;

  const int n_ns4 = N * HD / 4;
  const int n_nv4 = N * 3 * HD / 4;
  init_out_kernel<<<2048, 256, 0, stream>>>(
      (const f32x4*)node_scalar, (const f32x4*)node_vector, (f32x4*)d_out, n_ns4, n_nv4);

  conv_bf16_kernel<<<(n_nv4 + 255) / 256, 256, 0, stream>>>(
      (const f32x4*)node_vector, (ushort4*)nv_bf, n_nv4);

  tconv_kernel<<<192, 256, 0, stream>>>(mlp_p[3],  w2t_sche);
  tconv_kernel<<<192, 256, 0, stream>>>(mlp_p[9],  w2t_fche);
  tconv_kernel<<<192, 256, 0, stream>>>(mlp_p[15], w2t_svdw);
  tconv_kernel<<<192, 256, 0, stream>>>(mlp_p[21], w2t_fvdw);

  for (int br = 0; br < 2; br++) {
    const int*   edge = br == 0 ? che_edge : vdw_edge;
    const float* diff = br == 0 ? che_diff : vdw_diff;
    const float* dist = br == 0 ? che_dist : vdw_dist;
    const float* rbf  = br == 0 ? che_rbf  : vdw_rbf;
    const int    E    = br == 0 ? E_che : E_vdw;
    const float* const* sp = &mlp_p[br == 0 ? 0 : 12];
    const float* const* fp = &mlp_p[br == 0 ? 6 : 18];
    const unsigned short* w2t_s = br == 0 ? w2t_sche : w2t_svdw;
    const unsigned short* w2t_f = br == 0 ? w2t_fche : w2t_fvdw;

    node_mlp_hybrid<<<(N + 63) / 64, 256, 0, stream>>>(
        node_scalar, sp[0], sp[1], sp[2], w2t_s, sp[4], sp[5], so_bf, N);

    zero_int_kernel<<<(N + 255) / 256, 256, 0, stream>>>(counts, N);
    hist_kernel<<<(E + 255) / 256, 256, 0, stream>>>(edge, counts, E);
    scan_partial_kernel<<<nb_scan, 256, 0, stream>>>(counts, partials, N);
    scan_partials_kernel<<<1, 256, 0, stream>>>(partials, nb_scan);
    scan_write_kernel<<<nb_scan, 256, 0, stream>>>(counts, partials, offsets, cursor, N, E);
    scatter_ids_kernel<<<(E + 255) / 256, 256, 0, stream>>>(edge, cursor, edge_list, E);

    edge_mfma_reduce_kernel<<<(E + 63) / 64, 256, 0, stream>>>(
        so_bf, nv_bf, edge, diff, dist, rbf, edge_list, offsets,
        fp[0], fp[1], fp[2], w2t_f, fp[4], fp[5],
        (float*)d_out, N, E);
  }
}